// Round 6
// baseline (644.132 us; speedup 1.0000x reference)
//
#include <hip/hip_runtime.h>

// ---------------------------------------------------------------------------
// 2-layer GAT (PyG GATConv), fp32, MI355X.
// R6: k_gemm rewritten — R4/R5's per-kk global B-loads made the inner loop
//     vmcnt-bound (157us, VALUBusy 31%). Now: A^T and B both staged in LDS,
//     BK=16, software prefetch (regs->LDS->sync->issue next global loads->
//     compute). Inner loop is pure ds_read_b128 + FMA -> VALU-bound.
//     Everything else unchanged from R5 (aggr inline-weights + octet split).
// ---------------------------------------------------------------------------

__global__ __launch_bounds__(256)
void k_hist(const int* __restrict__ dstv, int* __restrict__ cnt, int E) {
  int i = blockIdx.x * 256 + threadIdx.x;
  if (i < E) atomicAdd(&cnt[dstv[i]], 1);
}

__global__ __launch_bounds__(256)
void k_scan_local(const int* __restrict__ cnt, int* __restrict__ rowptr,
                  int* __restrict__ partials, int N) {
  __shared__ int sm[256];
  int gid = blockIdx.x * 256 + threadIdx.x;
  int v = (gid < N) ? cnt[gid] : 0;
  sm[threadIdx.x] = v;
  __syncthreads();
  for (int off = 1; off < 256; off <<= 1) {
    int t = (threadIdx.x >= (unsigned)off) ? sm[threadIdx.x - off] : 0;
    __syncthreads();
    sm[threadIdx.x] += t;
    __syncthreads();
  }
  if (gid < N) rowptr[gid] = sm[threadIdx.x] - v;  // exclusive
  if (threadIdx.x == 255) partials[blockIdx.x] = sm[255];
}

__global__ __launch_bounds__(256)
void k_scan_part(int* __restrict__ partials, int nb) {
  __shared__ int sm[256];
  int t = threadIdx.x;
  int v = (t < nb) ? partials[t] : 0;
  sm[t] = v;
  __syncthreads();
  for (int off = 1; off < 256; off <<= 1) {
    int u = (t >= off) ? sm[t - off] : 0;
    __syncthreads();
    sm[t] += u;
    __syncthreads();
  }
  if (t < nb) partials[t] = sm[t] - v;  // exclusive
}

__global__ __launch_bounds__(256)
void k_scan_add(int* __restrict__ rowptr, const int* __restrict__ partials,
                int* __restrict__ cursor, int N, int E) {
  int gid = blockIdx.x * 256 + threadIdx.x;
  if (gid < N) {
    int rp = rowptr[gid] + partials[blockIdx.x];
    rowptr[gid] = rp;
    cursor[gid] = rp;
  }
  if (gid == 0) rowptr[N] = E;
}

__global__ __launch_bounds__(256)
void k_scatter(const int* __restrict__ srcv, const int* __restrict__ dstv,
               int* __restrict__ cursor, int* __restrict__ col, int E) {
  int i = blockIdx.x * 256 + threadIdx.x;
  if (i < E) {
    int p = atomicAdd(&cursor[dstv[i]], 1);
    col[p] = srcv[i];
  }
}

// ---------------------------------------------------------------------------
// fp32 GEMM: C[N,256] = A[N,K] @ W[K,256]. 128x128 tile, 16x16 threads, 8x8
// microtile, BK=16. A transposed in LDS (At[16][132]); B in LDS
// (Bs[16][132]). Prefetch pipeline: regs->LDS, sync, issue next global
// loads, compute 16 kks from LDS, sync. Fused attention-score epilogue.
// Thread t loads: A row t>>1, k-offset (t&1)*8 (+0..7);
//                 B row t>>4, cols (t&15)*8 (+0..7). Both fully coalesced.
// ---------------------------------------------------------------------------
__global__ __launch_bounds__(256)
void k_gemm(const float* __restrict__ A, const float* __restrict__ W,
            float* __restrict__ C, int Nrows, int K,
            const float* __restrict__ att_s, const float* __restrict__ att_d,
            float* __restrict__ a_s, float* __restrict__ a_d) {
  __shared__ float At[16][132];
  __shared__ float Bs[16][132];
  const int t  = threadIdx.x;
  const int tx = t & 15;
  const int ty = t >> 4;
  const int row0 = blockIdx.x * 128;
  const int col0 = blockIdx.y * 128;

  const int arow = t >> 1;          // 0..127
  const int akk  = (t & 1) * 8;     // 0 or 8
  const int bkk  = t >> 4;          // 0..15
  const int bcol = (t & 15) * 8;    // 0..120

  float acc[8][8] = {};

  // prefetch tile 0
  float4 a0 = make_float4(0.f, 0.f, 0.f, 0.f), a1 = a0;
  {
    int gr = row0 + arow;
    if (gr < Nrows) {
      const float* ap = A + (size_t)gr * K + akk;
      a0 = *(const float4*)(ap);
      a1 = *(const float4*)(ap + 4);
    }
  }
  float4 b0, b1;
  {
    const float* wp = W + (size_t)bkk * 256 + col0 + bcol;
    b0 = *(const float4*)(wp);
    b1 = *(const float4*)(wp + 4);
  }

  for (int k0 = 0; k0 < K; k0 += 16) {
    // ---- commit prefetched tile to LDS
    At[akk + 0][arow] = a0.x; At[akk + 1][arow] = a0.y;
    At[akk + 2][arow] = a0.z; At[akk + 3][arow] = a0.w;
    At[akk + 4][arow] = a1.x; At[akk + 5][arow] = a1.y;
    At[akk + 6][arow] = a1.z; At[akk + 7][arow] = a1.w;
    *(float4*)(&Bs[bkk][bcol])     = b0;
    *(float4*)(&Bs[bkk][bcol + 4]) = b1;
    __syncthreads();

    // ---- issue next tile's global loads (latency hidden under compute)
    if (k0 + 16 < K) {
      int gr = row0 + arow;
      if (gr < Nrows) {
        const float* ap = A + (size_t)gr * K + k0 + 16 + akk;
        a0 = *(const float4*)(ap);
        a1 = *(const float4*)(ap + 4);
      } else {
        a0 = make_float4(0.f, 0.f, 0.f, 0.f); a1 = a0;
      }
      const float* wp = W + (size_t)(k0 + 16 + bkk) * 256 + col0 + bcol;
      b0 = *(const float4*)(wp);
      b1 = *(const float4*)(wp + 4);
    }

    // ---- compute from LDS
#pragma unroll
    for (int kk = 0; kk < 16; kk++) {
      float4 av0 = *(const float4*)(&At[kk][ty * 8]);
      float4 av1 = *(const float4*)(&At[kk][ty * 8 + 4]);
      float4 bv0 = *(const float4*)(&Bs[kk][tx * 8]);
      float4 bv1 = *(const float4*)(&Bs[kk][tx * 8 + 4]);
      float ar[8] = {av0.x, av0.y, av0.z, av0.w, av1.x, av1.y, av1.z, av1.w};
      float br[8] = {bv0.x, bv0.y, bv0.z, bv0.w, bv1.x, bv1.y, bv1.z, bv1.w};
#pragma unroll
      for (int i = 0; i < 8; i++)
#pragma unroll
        for (int j = 0; j < 8; j++)
          acc[i][j] += ar[i] * br[j];
    }
    __syncthreads();
  }

#pragma unroll
  for (int i = 0; i < 8; i++) {
    int gr = row0 + ty * 8 + i;
    if (gr < Nrows) {
      float* cp = C + (size_t)gr * 256 + col0 + tx * 8;
      *(float4*)(cp)     = make_float4(acc[i][0], acc[i][1], acc[i][2], acc[i][3]);
      *(float4*)(cp + 4) = make_float4(acc[i][4], acc[i][5], acc[i][6], acc[i][7]);
    }
  }

  // ---- fused attention-score epilogue
  const int cbase = col0 + tx * 8;
  float asv[8], adv[8];
#pragma unroll
  for (int j = 0; j < 8; j++) { asv[j] = att_s[cbase + j]; adv[j] = att_d[cbase + j]; }
  const int head = cbase >> 6;  // tx*8 never straddles a 64-col boundary
#pragma unroll
  for (int i = 0; i < 8; i++) {
    float ps = 0.f, pd = 0.f;
#pragma unroll
    for (int j = 0; j < 8; j++) { ps += acc[i][j] * asv[j]; pd += acc[i][j] * adv[j]; }
    ps += __shfl_xor(ps, 1); pd += __shfl_xor(pd, 1);
    ps += __shfl_xor(ps, 2); pd += __shfl_xor(pd, 2);
    ps += __shfl_xor(ps, 4); pd += __shfl_xor(pd, 4);
    if ((tx & 7) == 0) {
      int gr = row0 + ty * 8 + i;
      if (gr < Nrows) {
        atomicAdd(&a_s[(size_t)gr * 4 + head], ps);
        atomicAdd(&a_d[(size_t)gr * 4 + head], pd);
      }
    }
  }
}

// ---------------------------------------------------------------------------
// Aggregation: one wave per (node, channel-half); octet mapping blockIdx%8:
// slots 0..3 -> half 0 (heads 0,1), 4..7 -> half 1 (heads 2,3).
// Chunk stage: lane gathers a_s[col] (float2, L2-resident 800KB), computes
// w = exp(leaky(a_s+a_d)) inline, stages (src,w) in LDS. j-loop: gather h
// rows + FMA; denominator accumulated from the staged weights (free).
// LAYER 1: relu(acc/den + bias) -> [N,256]. LAYER 2: acc/den -> temp.
// ---------------------------------------------------------------------------
template <int LAYER>
__global__ __launch_bounds__(256)
void k_aggr(const float* __restrict__ hsrc, const int* __restrict__ rowptr,
            const int* __restrict__ col, const float* __restrict__ a_s,
            const float* __restrict__ a_d, const float* __restrict__ bias,
            float* __restrict__ outp, int N) {
  __shared__ int   s_sh[4][64];
  __shared__ float w_sh[4][128];
  const int wv = threadIdx.x >> 6;
  const int lane = threadIdx.x & 63;
  const int g = blockIdx.x >> 3;
  const int s8 = blockIdx.x & 7;
  const int half = s8 >> 2;
  const int node = g * 16 + (s8 & 3) * 4 + wv;
  if (node >= N) return;
  const int hd = lane >> 5;  // head within half
  const int beg = rowptr[node], end = rowptr[node + 1];
  const float2 adst = *(const float2*)(a_d + (size_t)node * 4 + half * 2);

  float2 acc = make_float2(0.f, 0.f);
  float wsum = 0.f;

  for (int c0 = beg; c0 < end; c0 += 64) {
    int nc = min(64, end - c0);
    int s = 0;
    float w0 = 0.f, w1 = 0.f;
    if (lane < nc) {
      s = col[c0 + lane];
      float2 asr = *(const float2*)(a_s + (size_t)s * 4 + half * 2);
      float e0 = asr.x + adst.x; e0 = e0 > 0.f ? e0 : 0.2f * e0;
      float e1 = asr.y + adst.y; e1 = e1 > 0.f ? e1 : 0.2f * e1;
      w0 = __expf(e0); w1 = __expf(e1);
    }
    s_sh[wv][lane] = s;
    *(float2*)(&w_sh[wv][lane * 2]) = make_float2(w0, w1);
    asm volatile("s_waitcnt lgkmcnt(0)" ::: "memory");

    const float* wrow = &w_sh[wv][hd];
    const int*   srow = &s_sh[wv][0];
    const float* hbase = hsrc + half * 128 + lane * 2;
    int j = 0;
    for (; j + 4 <= nc; j += 4) {
      int sj0 = srow[j], sj1 = srow[j + 1], sj2 = srow[j + 2], sj3 = srow[j + 3];
      float ww0 = wrow[2 * j],     ww1 = wrow[2 * j + 2];
      float ww2 = wrow[2 * j + 4], ww3 = wrow[2 * j + 6];
      float2 h0 = *(const float2*)(hbase + (size_t)sj0 * 256);
      float2 h1 = *(const float2*)(hbase + (size_t)sj1 * 256);
      float2 h2 = *(const float2*)(hbase + (size_t)sj2 * 256);
      float2 h3 = *(const float2*)(hbase + (size_t)sj3 * 256);
      wsum += ww0 + ww1 + ww2 + ww3;
      acc.x += ww0 * h0.x; acc.y += ww0 * h0.y;
      acc.x += ww1 * h1.x; acc.y += ww1 * h1.y;
      acc.x += ww2 * h2.x; acc.y += ww2 * h2.y;
      acc.x += ww3 * h3.x; acc.y += ww3 * h3.y;
    }
    for (; j < nc; j++) {
      int sj = srow[j];
      float w = wrow[2 * j];
      float2 hv = *(const float2*)(hbase + (size_t)sj * 256);
      wsum += w;
      acc.x += w * hv.x; acc.y += w * hv.y;
    }
  }

  float inv = 1.0f / wsum;  // deg>=1 via self-loop => wsum>0
  float2 v = make_float2(acc.x * inv, acc.y * inv);
  const size_t o = (size_t)node * 256 + half * 128 + lane * 2;
  if (LAYER == 1) {
    float2 bv = *(const float2*)(bias + half * 128 + lane * 2);
    v.x = fmaxf(v.x + bv.x, 0.f);
    v.y = fmaxf(v.y + bv.y, 0.f);
    *(float2*)(outp + o) = v;
  } else {
    *(float2*)(outp + o) = v;  // per-head normalized values; k_final mixes
  }
}

// ---------------------------------------------------------------------------
// Layer-2 epilogue: head-mean + bias + relu + softmax(64). One wave per node.
// ---------------------------------------------------------------------------
__global__ __launch_bounds__(256)
void k_final(const float* __restrict__ t, const float* __restrict__ b2,
             float* __restrict__ out, int N) {
  int node = (int)((blockIdx.x * 256u + threadIdx.x) >> 6);
  int lane = threadIdx.x & 63;
  if (node >= N) return;
  const float* tr = t + (size_t)node * 256;
  float v = 0.25f * (tr[lane] + tr[64 + lane] + tr[128 + lane] + tr[192 + lane]) + b2[lane];
  v = fmaxf(v, 0.f);
  float mx = v;
  for (int off = 32; off; off >>= 1) mx = fmaxf(mx, __shfl_xor(mx, off));
  float e = __expf(v - mx);
  float sum = e;
  for (int off = 32; off; off >>= 1) sum += __shfl_xor(sum, off);
  out[(size_t)node * 64 + lane] = e / sum;
}

// ---------------------------------------------------------------------------

extern "C" void kernel_launch(void* const* d_in, const int* in_sizes, int n_in,
                              void* d_out, int out_size, void* d_ws, size_t ws_size,
                              hipStream_t stream) {
  const float* x   = (const float*)d_in[0];
  const int*   ei  = (const int*)d_in[1];
  const float* W1  = (const float*)d_in[2];
  const float* as1 = (const float*)d_in[3];
  const float* ad1 = (const float*)d_in[4];
  const float* b1  = (const float*)d_in[5];
  const float* W2  = (const float*)d_in[6];
  const float* as2 = (const float*)d_in[7];
  const float* ad2 = (const float*)d_in[8];
  const float* b2  = (const float*)d_in[9];
  float* out = (float*)d_out;

  const int N = in_sizes[0] / 128;
  const int E = in_sizes[1] / 2;
  const int* srcv = ei;
  const int* dstv = ei + E;

  float* h    = (float*)d_ws;             // [N,256]
  float* hb   = h + (size_t)N * 256;      // [N,256] (layer-1 out / layer-2 temp)
  float* zbuf = hb + (size_t)N * 256;     // 16N: a_s1,a_d1,a_s2,a_d2
  float* a_s1 = zbuf;
  float* a_d1 = a_s1 + (size_t)N * 4;
  float* a_s2 = a_d1 + (size_t)N * 4;
  float* a_d2 = a_s2 + (size_t)N * 4;
  int*   rowptr = (int*)(zbuf + (size_t)N * 16);  // [N+1] (+pad)
  int*   cnt    = rowptr + (N + 4);               // [N]
  int*   cursor = cnt + N;                        // [N]
  int*   col    = cursor + N;                     // [E]
  int*   partials = col + E;                      // [<=256]

  const int nb = (N + 255) / 256;
  const int eb = (E + 255) / 256;

  hipMemsetAsync(cnt, 0, (size_t)N * 4, stream);
  hipMemsetAsync(zbuf, 0, (size_t)N * 16 * 4, stream);
  k_hist<<<eb, 256, 0, stream>>>(dstv, cnt, E);
  k_scan_local<<<nb, 256, 0, stream>>>(cnt, rowptr, partials, N);
  k_scan_part<<<1, 256, 0, stream>>>(partials, nb);
  k_scan_add<<<nb, 256, 0, stream>>>(rowptr, partials, cursor, N, E);
  k_scatter<<<eb, 256, 0, stream>>>(srcv, dstv, cursor, col, E);

  dim3 gg((N + 127) / 128, 2);
  const int ab = ((N + 15) / 16) * 8;  // octet-mapped (node, half) waves
  const int wb = (N + 3) / 4;          // wave-per-node

  k_gemm<<<gg, 256, 0, stream>>>(x, W1, h, N, 128, as1, ad1, a_s1, a_d1);
  k_aggr<1><<<ab, 256, 0, stream>>>(h, rowptr, col, a_s1, a_d1, b1, hb, N);
  k_gemm<<<gg, 256, 0, stream>>>(hb, W2, h, N, 256, as2, ad2, a_s2, a_d2);
  k_aggr<2><<<ab, 256, 0, stream>>>(h, rowptr, col, a_s2, a_d2, b2, hb, N);
  k_final<<<wb, 256, 0, stream>>>(hb, b2, out, N);
}

// Round 7
// 606.292 us; speedup vs baseline: 1.0624x; 1.0624x over previous
//
#include <hip/hip_runtime.h>

// ---------------------------------------------------------------------------
// 2-layer GAT (PyG GATConv), fp32, MI355X.
// R7: k_gemm — quarter-wave 4x4 swizzle: each 16-lane quarter-wave spans
//     4 tx x 4 ty so BOTH A and B LDS reads are 4 addrs x 32B = all 32 banks
//     (4-lane broadcast each) -> conflict-free (R6 had 8M conflicts: 16
//     distinct B addrs at 32B stride = 4-way). BK=8 (LDS 8.4KB, VGPR ~110
//     -> 4 waves/SIMD). Epilogue reduce over tx bits = lane{0,1,4}.
//     aggr/CSR unchanged from R5.
// ---------------------------------------------------------------------------

__global__ __launch_bounds__(256)
void k_hist(const int* __restrict__ dstv, int* __restrict__ cnt, int E) {
  int i = blockIdx.x * 256 + threadIdx.x;
  if (i < E) atomicAdd(&cnt[dstv[i]], 1);
}

__global__ __launch_bounds__(256)
void k_scan_local(const int* __restrict__ cnt, int* __restrict__ rowptr,
                  int* __restrict__ partials, int N) {
  __shared__ int sm[256];
  int gid = blockIdx.x * 256 + threadIdx.x;
  int v = (gid < N) ? cnt[gid] : 0;
  sm[threadIdx.x] = v;
  __syncthreads();
  for (int off = 1; off < 256; off <<= 1) {
    int t = (threadIdx.x >= (unsigned)off) ? sm[threadIdx.x - off] : 0;
    __syncthreads();
    sm[threadIdx.x] += t;
    __syncthreads();
  }
  if (gid < N) rowptr[gid] = sm[threadIdx.x] - v;  // exclusive
  if (threadIdx.x == 255) partials[blockIdx.x] = sm[255];
}

__global__ __launch_bounds__(256)
void k_scan_part(int* __restrict__ partials, int nb) {
  __shared__ int sm[256];
  int t = threadIdx.x;
  int v = (t < nb) ? partials[t] : 0;
  sm[t] = v;
  __syncthreads();
  for (int off = 1; off < 256; off <<= 1) {
    int u = (t >= off) ? sm[t - off] : 0;
    __syncthreads();
    sm[t] += u;
    __syncthreads();
  }
  if (t < nb) partials[t] = sm[t] - v;  // exclusive
}

__global__ __launch_bounds__(256)
void k_scan_add(int* __restrict__ rowptr, const int* __restrict__ partials,
                int* __restrict__ cursor, int N, int E) {
  int gid = blockIdx.x * 256 + threadIdx.x;
  if (gid < N) {
    int rp = rowptr[gid] + partials[blockIdx.x];
    rowptr[gid] = rp;
    cursor[gid] = rp;
  }
  if (gid == 0) rowptr[N] = E;
}

__global__ __launch_bounds__(256)
void k_scatter(const int* __restrict__ srcv, const int* __restrict__ dstv,
               int* __restrict__ cursor, int* __restrict__ col, int E) {
  int i = blockIdx.x * 256 + threadIdx.x;
  if (i < E) {
    int p = atomicAdd(&cursor[dstv[i]], 1);
    col[p] = srcv[i];
  }
}

// ---------------------------------------------------------------------------
// fp32 GEMM: C[N,256] = A[N,K] @ W[K,256]. 128x128 tile, 8x8 micro, BK=8.
// Quarter-wave-swizzled (tx,ty): tx bits = t{0,1,4,6}, ty bits = t{2,3,5,7}.
// Each wave owns a 64x64 quadrant; head = f(t6) is wave-uniform.
// A^T and B staged in LDS; single-depth register prefetch.
// ---------------------------------------------------------------------------
__global__ __launch_bounds__(256)
void k_gemm(const float* __restrict__ A, const float* __restrict__ W,
            float* __restrict__ C, int Nrows, int K,
            const float* __restrict__ att_s, const float* __restrict__ att_d,
            float* __restrict__ a_s, float* __restrict__ a_d) {
  __shared__ float At[8][132];
  __shared__ float Bs[8][132];
  const int t = threadIdx.x;
  const int tx = (t & 3) | (((t >> 4) & 1) << 2) | (((t >> 6) & 1) << 3);
  const int ty = ((t >> 2) & 3) | (((t >> 5) & 1) << 2) | (((t >> 7) & 1) << 3);
  const int row0 = blockIdx.x * 128;
  const int col0 = blockIdx.y * 128;

  const int arow = t >> 1;          // 0..127
  const int akk  = (t & 1) * 4;     // 0 or 4
  const int bkk  = t >> 5;          // 0..7
  const int bcol = (t & 31) * 4;    // 0..124

  float acc[8][8] = {};

  // prefetch tile 0
  float4 pa = make_float4(0.f, 0.f, 0.f, 0.f);
  {
    int gr = row0 + arow;
    if (gr < Nrows) pa = *(const float4*)(A + (size_t)gr * K + akk);
  }
  float4 pb = *(const float4*)(W + (size_t)bkk * 256 + col0 + bcol);

  for (int k0 = 0; k0 < K; k0 += 8) {
    // commit prefetched tile to LDS
    At[akk + 0][arow] = pa.x; At[akk + 1][arow] = pa.y;
    At[akk + 2][arow] = pa.z; At[akk + 3][arow] = pa.w;
    *(float4*)(&Bs[bkk][bcol]) = pb;
    __syncthreads();

    // issue next tile's global loads (hidden under compute)
    if (k0 + 8 < K) {
      int gr = row0 + arow;
      if (gr < Nrows)
        pa = *(const float4*)(A + (size_t)gr * K + k0 + 8 + akk);
      else
        pa = make_float4(0.f, 0.f, 0.f, 0.f);
      pb = *(const float4*)(W + (size_t)(k0 + 8 + bkk) * 256 + col0 + bcol);
    }

    // compute from LDS (conflict-free under the quarter-wave swizzle)
#pragma unroll
    for (int kk = 0; kk < 8; kk++) {
      float4 av0 = *(const float4*)(&At[kk][ty * 8]);
      float4 av1 = *(const float4*)(&At[kk][ty * 8 + 4]);
      float4 bv0 = *(const float4*)(&Bs[kk][tx * 8]);
      float4 bv1 = *(const float4*)(&Bs[kk][tx * 8 + 4]);
      float ar[8] = {av0.x, av0.y, av0.z, av0.w, av1.x, av1.y, av1.z, av1.w};
      float br[8] = {bv0.x, bv0.y, bv0.z, bv0.w, bv1.x, bv1.y, bv1.z, bv1.w};
#pragma unroll
      for (int i = 0; i < 8; i++)
#pragma unroll
        for (int j = 0; j < 8; j++)
          acc[i][j] += ar[i] * br[j];
    }
    __syncthreads();
  }

#pragma unroll
  for (int i = 0; i < 8; i++) {
    int gr = row0 + ty * 8 + i;
    if (gr < Nrows) {
      float* cp = C + (size_t)gr * 256 + col0 + tx * 8;
      *(float4*)(cp)     = make_float4(acc[i][0], acc[i][1], acc[i][2], acc[i][3]);
      *(float4*)(cp + 4) = make_float4(acc[i][4], acc[i][5], acc[i][6], acc[i][7]);
    }
  }

  // ---- fused attention-score epilogue
  // tx bits live in lane bits {0,1,4} (bit3 of tx = t6, wave-uniform).
  const int cbase = col0 + tx * 8;
  float asv[8], adv[8];
#pragma unroll
  for (int j = 0; j < 8; j++) { asv[j] = att_s[cbase + j]; adv[j] = att_d[cbase + j]; }
  const int head = cbase >> 6;  // wave-uniform
#pragma unroll
  for (int i = 0; i < 8; i++) {
    float ps = 0.f, pd = 0.f;
#pragma unroll
    for (int j = 0; j < 8; j++) { ps += acc[i][j] * asv[j]; pd += acc[i][j] * adv[j]; }
    ps += __shfl_xor(ps, 1);  pd += __shfl_xor(pd, 1);
    ps += __shfl_xor(ps, 2);  pd += __shfl_xor(pd, 2);
    ps += __shfl_xor(ps, 16); pd += __shfl_xor(pd, 16);
    if ((t & 19) == 0) {  // lane bits 0,1,4 clear -> one writer per (row,head)
      int gr = row0 + ty * 8 + i;
      if (gr < Nrows) {
        atomicAdd(&a_s[(size_t)gr * 4 + head], ps);
        atomicAdd(&a_d[(size_t)gr * 4 + head], pd);
      }
    }
  }
}

// ---------------------------------------------------------------------------
// Aggregation: one wave per (node, channel-half); octet mapping blockIdx%8:
// slots 0..3 -> half 0 (heads 0,1), 4..7 -> half 1 (heads 2,3).
// Chunk stage: lane gathers a_s[col] (float2, L2-resident 800KB), computes
// w = exp(leaky(a_s+a_d)) inline, stages (src,w) in LDS. j-loop: gather h
// rows + FMA; denominator accumulated from the staged weights (free).
// LAYER 1: relu(acc/den + bias) -> [N,256]. LAYER 2: acc/den -> temp.
// ---------------------------------------------------------------------------
template <int LAYER>
__global__ __launch_bounds__(256)
void k_aggr(const float* __restrict__ hsrc, const int* __restrict__ rowptr,
            const int* __restrict__ col, const float* __restrict__ a_s,
            const float* __restrict__ a_d, const float* __restrict__ bias,
            float* __restrict__ outp, int N) {
  __shared__ int   s_sh[4][64];
  __shared__ float w_sh[4][128];
  const int wv = threadIdx.x >> 6;
  const int lane = threadIdx.x & 63;
  const int g = blockIdx.x >> 3;
  const int s8 = blockIdx.x & 7;
  const int half = s8 >> 2;
  const int node = g * 16 + (s8 & 3) * 4 + wv;
  if (node >= N) return;
  const int hd = lane >> 5;  // head within half
  const int beg = rowptr[node], end = rowptr[node + 1];
  const float2 adst = *(const float2*)(a_d + (size_t)node * 4 + half * 2);

  float2 acc = make_float2(0.f, 0.f);
  float wsum = 0.f;

  for (int c0 = beg; c0 < end; c0 += 64) {
    int nc = min(64, end - c0);
    int s = 0;
    float w0 = 0.f, w1 = 0.f;
    if (lane < nc) {
      s = col[c0 + lane];
      float2 asr = *(const float2*)(a_s + (size_t)s * 4 + half * 2);
      float e0 = asr.x + adst.x; e0 = e0 > 0.f ? e0 : 0.2f * e0;
      float e1 = asr.y + adst.y; e1 = e1 > 0.f ? e1 : 0.2f * e1;
      w0 = __expf(e0); w1 = __expf(e1);
    }
    s_sh[wv][lane] = s;
    *(float2*)(&w_sh[wv][lane * 2]) = make_float2(w0, w1);
    asm volatile("s_waitcnt lgkmcnt(0)" ::: "memory");

    const float* wrow = &w_sh[wv][hd];
    const int*   srow = &s_sh[wv][0];
    const float* hbase = hsrc + half * 128 + lane * 2;
    int j = 0;
    for (; j + 4 <= nc; j += 4) {
      int sj0 = srow[j], sj1 = srow[j + 1], sj2 = srow[j + 2], sj3 = srow[j + 3];
      float ww0 = wrow[2 * j],     ww1 = wrow[2 * j + 2];
      float ww2 = wrow[2 * j + 4], ww3 = wrow[2 * j + 6];
      float2 h0 = *(const float2*)(hbase + (size_t)sj0 * 256);
      float2 h1 = *(const float2*)(hbase + (size_t)sj1 * 256);
      float2 h2 = *(const float2*)(hbase + (size_t)sj2 * 256);
      float2 h3 = *(const float2*)(hbase + (size_t)sj3 * 256);
      wsum += ww0 + ww1 + ww2 + ww3;
      acc.x += ww0 * h0.x; acc.y += ww0 * h0.y;
      acc.x += ww1 * h1.x; acc.y += ww1 * h1.y;
      acc.x += ww2 * h2.x; acc.y += ww2 * h2.y;
      acc.x += ww3 * h3.x; acc.y += ww3 * h3.y;
    }
    for (; j < nc; j++) {
      int sj = srow[j];
      float w = wrow[2 * j];
      float2 hv = *(const float2*)(hbase + (size_t)sj * 256);
      wsum += w;
      acc.x += w * hv.x; acc.y += w * hv.y;
    }
  }

  float inv = 1.0f / wsum;  // deg>=1 via self-loop => wsum>0
  float2 v = make_float2(acc.x * inv, acc.y * inv);
  const size_t o = (size_t)node * 256 + half * 128 + lane * 2;
  if (LAYER == 1) {
    float2 bv = *(const float2*)(bias + half * 128 + lane * 2);
    v.x = fmaxf(v.x + bv.x, 0.f);
    v.y = fmaxf(v.y + bv.y, 0.f);
    *(float2*)(outp + o) = v;
  } else {
    *(float2*)(outp + o) = v;  // per-head normalized values; k_final mixes
  }
}

// ---------------------------------------------------------------------------
// Layer-2 epilogue: head-mean + bias + relu + softmax(64). One wave per node.
// ---------------------------------------------------------------------------
__global__ __launch_bounds__(256)
void k_final(const float* __restrict__ t, const float* __restrict__ b2,
             float* __restrict__ out, int N) {
  int node = (int)((blockIdx.x * 256u + threadIdx.x) >> 6);
  int lane = threadIdx.x & 63;
  if (node >= N) return;
  const float* tr = t + (size_t)node * 256;
  float v = 0.25f * (tr[lane] + tr[64 + lane] + tr[128 + lane] + tr[192 + lane]) + b2[lane];
  v = fmaxf(v, 0.f);
  float mx = v;
  for (int off = 32; off; off >>= 1) mx = fmaxf(mx, __shfl_xor(mx, off));
  float e = __expf(v - mx);
  float sum = e;
  for (int off = 32; off; off >>= 1) sum += __shfl_xor(sum, off);
  out[(size_t)node * 64 + lane] = e / sum;
}

// ---------------------------------------------------------------------------

extern "C" void kernel_launch(void* const* d_in, const int* in_sizes, int n_in,
                              void* d_out, int out_size, void* d_ws, size_t ws_size,
                              hipStream_t stream) {
  const float* x   = (const float*)d_in[0];
  const int*   ei  = (const int*)d_in[1];
  const float* W1  = (const float*)d_in[2];
  const float* as1 = (const float*)d_in[3];
  const float* ad1 = (const float*)d_in[4];
  const float* b1  = (const float*)d_in[5];
  const float* W2  = (const float*)d_in[6];
  const float* as2 = (const float*)d_in[7];
  const float* ad2 = (const float*)d_in[8];
  const float* b2  = (const float*)d_in[9];
  float* out = (float*)d_out;

  const int N = in_sizes[0] / 128;
  const int E = in_sizes[1] / 2;
  const int* srcv = ei;
  const int* dstv = ei + E;

  float* h    = (float*)d_ws;             // [N,256]
  float* hb   = h + (size_t)N * 256;      // [N,256] (layer-1 out / layer-2 temp)
  float* zbuf = hb + (size_t)N * 256;     // 16N: a_s1,a_d1,a_s2,a_d2
  float* a_s1 = zbuf;
  float* a_d1 = a_s1 + (size_t)N * 4;
  float* a_s2 = a_d1 + (size_t)N * 4;
  float* a_d2 = a_s2 + (size_t)N * 4;
  int*   rowptr = (int*)(zbuf + (size_t)N * 16);  // [N+1] (+pad)
  int*   cnt    = rowptr + (N + 4);               // [N]
  int*   cursor = cnt + N;                        // [N]
  int*   col    = cursor + N;                     // [E]
  int*   partials = col + E;                      // [<=256]

  const int nb = (N + 255) / 256;
  const int eb = (E + 255) / 256;

  hipMemsetAsync(cnt, 0, (size_t)N * 4, stream);
  hipMemsetAsync(zbuf, 0, (size_t)N * 16 * 4, stream);
  k_hist<<<eb, 256, 0, stream>>>(dstv, cnt, E);
  k_scan_local<<<nb, 256, 0, stream>>>(cnt, rowptr, partials, N);
  k_scan_part<<<1, 256, 0, stream>>>(partials, nb);
  k_scan_add<<<nb, 256, 0, stream>>>(rowptr, partials, cursor, N, E);
  k_scatter<<<eb, 256, 0, stream>>>(srcv, dstv, cursor, col, E);

  dim3 gg((N + 127) / 128, 2);
  const int ab = ((N + 15) / 16) * 8;  // octet-mapped (node, half) waves
  const int wb = (N + 3) / 4;          // wave-per-node

  k_gemm<<<gg, 256, 0, stream>>>(x, W1, h, N, 128, as1, ad1, a_s1, a_d1);
  k_aggr<1><<<ab, 256, 0, stream>>>(h, rowptr, col, a_s1, a_d1, b1, hb, N);
  k_gemm<<<gg, 256, 0, stream>>>(hb, W2, h, N, 256, as2, ad2, a_s2, a_d2);
  k_aggr<2><<<ab, 256, 0, stream>>>(h, rowptr, col, a_s2, a_d2, b2, hb, N);
  k_final<<<wb, 256, 0, stream>>>(hb, b2, out, N);
}

// Round 8
// 445.344 us; speedup vs baseline: 1.4464x; 1.3614x over previous
//
#include <hip/hip_runtime.h>

// ---------------------------------------------------------------------------
// 2-layer GAT (PyG GATConv), MI355X.
// R8: GEMMs moved to matrix cores via split-bf16 (Markidis 3-term):
//     A = Ah+Al (bf16), C ~= Ah*Bh + Al*Bh + Ah*Bl  (error ~2^-17 rel).
//     16x16x32 bf16 MFMA, block 128x128, 4 waves (2x2), wave tile 64x64,
//     BK=32, A/B staged in LDS as bf16 (pad row to 40 elems -> bank-uniform).
//     h stored bf16 -> aggr gather traffic halves; hb stored split-bf16 so
//     GEMM2 input stays near-exact; attention scores from fp32 accs in the
//     GEMM epilogue (one writer per (row,head) -> plain stores).
//     CSR/aggr structure otherwise as R7.
// ---------------------------------------------------------------------------

typedef __attribute__((ext_vector_type(8))) short short8;
typedef __attribute__((ext_vector_type(4))) float f32x4;

static __device__ __forceinline__ ushort f2bf(float f) {  // RNE
  uint u = __float_as_uint(f);
  return (ushort)((u + 0x7FFFu + ((u >> 16) & 1u)) >> 16);
}
static __device__ __forceinline__ float bf2f(ushort s) {
  return __uint_as_float(((uint)s) << 16);
}

// ----------------------------- CSR build -----------------------------------
__global__ __launch_bounds__(256)
void k_hist(const int* __restrict__ dstv, int* __restrict__ cnt, int E) {
  int i = blockIdx.x * 256 + threadIdx.x;
  if (i < E) atomicAdd(&cnt[dstv[i]], 1);
}

__global__ __launch_bounds__(256)
void k_scan_local(const int* __restrict__ cnt, int* __restrict__ rowptr,
                  int* __restrict__ partials, int N) {
  __shared__ int sm[256];
  int gid = blockIdx.x * 256 + threadIdx.x;
  int v = (gid < N) ? cnt[gid] : 0;
  sm[threadIdx.x] = v;
  __syncthreads();
  for (int off = 1; off < 256; off <<= 1) {
    int t = (threadIdx.x >= (unsigned)off) ? sm[threadIdx.x - off] : 0;
    __syncthreads();
    sm[threadIdx.x] += t;
    __syncthreads();
  }
  if (gid < N) rowptr[gid] = sm[threadIdx.x] - v;  // exclusive
  if (threadIdx.x == 255) partials[blockIdx.x] = sm[255];
}

__global__ __launch_bounds__(256)
void k_scan_part(int* __restrict__ partials, int nb) {
  __shared__ int sm[256];
  int t = threadIdx.x;
  int v = (t < nb) ? partials[t] : 0;
  sm[t] = v;
  __syncthreads();
  for (int off = 1; off < 256; off <<= 1) {
    int u = (t >= off) ? sm[t - off] : 0;
    __syncthreads();
    sm[t] += u;
    __syncthreads();
  }
  if (t < nb) partials[t] = sm[t] - v;  // exclusive
}

__global__ __launch_bounds__(256)
void k_scan_add(int* __restrict__ rowptr, const int* __restrict__ partials,
                int* __restrict__ cursor, int N, int E) {
  int gid = blockIdx.x * 256 + threadIdx.x;
  if (gid < N) {
    int rp = rowptr[gid] + partials[blockIdx.x];
    rowptr[gid] = rp;
    cursor[gid] = rp;
  }
  if (gid == 0) rowptr[N] = E;
}

__global__ __launch_bounds__(256)
void k_scatter(const int* __restrict__ srcv, const int* __restrict__ dstv,
               int* __restrict__ cursor, int* __restrict__ col, int E) {
  int i = blockIdx.x * 256 + threadIdx.x;
  if (i < E) {
    int p = atomicAdd(&cursor[dstv[i]], 1);
    col[p] = srcv[i];
  }
}

// ----------------------------- prep: splits --------------------------------
// x [N,128] fp32 -> x_h, x_l bf16 (RNE + residual).
__global__ __launch_bounds__(256)
void k_split_x(const float* __restrict__ x, ushort* __restrict__ xh,
               ushort* __restrict__ xl, int total4) {
  int gid = blockIdx.x * 256 + threadIdx.x;
  if (gid >= total4) return;
  float4 v = ((const float4*)x)[gid];
  ushort4 h, l;
  h.x = f2bf(v.x); l.x = f2bf(v.x - bf2f(h.x));
  h.y = f2bf(v.y); l.y = f2bf(v.y - bf2f(h.y));
  h.z = f2bf(v.z); l.z = f2bf(v.z - bf2f(h.z));
  h.w = f2bf(v.w); l.w = f2bf(v.w - bf2f(h.w));
  ((ushort4*)xh)[gid] = h;
  ((ushort4*)xl)[gid] = l;
}

// W [K,256] fp32 -> Wt_h, Wt_l [256][K] bf16 (transposed, split).
__global__ __launch_bounds__(256)
void k_prep_w(const float* __restrict__ W, ushort* __restrict__ wth,
              ushort* __restrict__ wtl, int K) {
  int gid = blockIdx.x * 256 + threadIdx.x;  // gid < K*256
  int c = gid & 255, k = gid >> 8;
  float w = W[(size_t)k * 256 + c];
  ushort h = f2bf(w);
  wth[(size_t)c * K + k] = h;
  wtl[(size_t)c * K + k] = f2bf(w - bf2f(h));
}

// ----------------------------- MFMA GEMM -----------------------------------
// C[N,256] = (Ah+Al)[N,K] @ (Bh+Bl)[K,256] with Bt stored [256][K].
// Block 128x128 (grid.y=2 col halves), 4 waves 2x2, wave tile 64x64 =
// 4x4 MFMA tiles of 16x16x32. 3-term split MFMA. Output: hout bf16 [N,256];
// epilogue computes a_s/a_d per (row, head) from fp32 accs (plain stores).
__global__ __launch_bounds__(256)
void k_gemm_mfma(const ushort* __restrict__ Ah, const ushort* __restrict__ Al,
                 const ushort* __restrict__ Bth, const ushort* __restrict__ Btl,
                 ushort* __restrict__ hout, int Nrows, int K,
                 const float* __restrict__ att_s, const float* __restrict__ att_d,
                 float* __restrict__ a_s, float* __restrict__ a_d) {
  __shared__ ushort As_h[128][40], As_l[128][40];
  __shared__ ushort Bs_h[128][40], Bs_l[128][40];
  const int t = threadIdx.x;
  const int lane = t & 63;
  const int w = t >> 6;
  const int wr = (w >> 1) * 64;
  const int wc = (w & 1) * 64;
  const int row0 = blockIdx.x * 128;
  const int col0 = blockIdx.y * 128;
  const int lrow = t >> 2;       // 0..63 staging index
  const int kc = (t & 3) * 8;    // k-chunk within BK=32

  f32x4 acc[4][4] = {};

  uint4 pa_h[2], pa_l[2], pb_h[2], pb_l[2];
  const uint4 z4 = make_uint4(0, 0, 0, 0);
#pragma unroll
  for (int p = 0; p < 2; p++) {
    int gr = row0 + p * 64 + lrow;
    if (gr < Nrows) {
      pa_h[p] = *(const uint4*)(Ah + (size_t)gr * K + kc);
      pa_l[p] = *(const uint4*)(Al + (size_t)gr * K + kc);
    } else { pa_h[p] = z4; pa_l[p] = z4; }
    int gc = col0 + p * 64 + lrow;
    pb_h[p] = *(const uint4*)(Bth + (size_t)gc * K + kc);
    pb_l[p] = *(const uint4*)(Btl + (size_t)gc * K + kc);
  }

  const int fr = lane & 15;
  const int fq = lane >> 4;

  for (int k0 = 0; k0 < K; k0 += 32) {
#pragma unroll
    for (int p = 0; p < 2; p++) {
      *(uint4*)(&As_h[p * 64 + lrow][kc]) = pa_h[p];
      *(uint4*)(&As_l[p * 64 + lrow][kc]) = pa_l[p];
      *(uint4*)(&Bs_h[p * 64 + lrow][kc]) = pb_h[p];
      *(uint4*)(&Bs_l[p * 64 + lrow][kc]) = pb_l[p];
    }
    __syncthreads();

    if (k0 + 32 < K) {
#pragma unroll
      for (int p = 0; p < 2; p++) {
        int gr = row0 + p * 64 + lrow;
        if (gr < Nrows) {
          pa_h[p] = *(const uint4*)(Ah + (size_t)gr * K + k0 + 32 + kc);
          pa_l[p] = *(const uint4*)(Al + (size_t)gr * K + k0 + 32 + kc);
        } else { pa_h[p] = z4; pa_l[p] = z4; }
        int gc = col0 + p * 64 + lrow;
        pb_h[p] = *(const uint4*)(Bth + (size_t)gc * K + k0 + 32 + kc);
        pb_l[p] = *(const uint4*)(Btl + (size_t)gc * K + k0 + 32 + kc);
      }
    }

    short8 fa_h[4], fa_l[4], fb_h[4], fb_l[4];
#pragma unroll
    for (int r = 0; r < 4; r++) {
      fa_h[r] = *(const short8*)(&As_h[wr + r * 16 + fr][fq * 8]);
      fa_l[r] = *(const short8*)(&As_l[wr + r * 16 + fr][fq * 8]);
    }
#pragma unroll
    for (int c = 0; c < 4; c++) {
      fb_h[c] = *(const short8*)(&Bs_h[wc + c * 16 + fr][fq * 8]);
      fb_l[c] = *(const short8*)(&Bs_l[wc + c * 16 + fr][fq * 8]);
    }
#pragma unroll
    for (int r = 0; r < 4; r++)
#pragma unroll
      for (int c = 0; c < 4; c++) {
        acc[r][c] = __builtin_amdgcn_mfma_f32_16x16x32_bf16(fa_h[r], fb_h[c], acc[r][c], 0, 0, 0);
        acc[r][c] = __builtin_amdgcn_mfma_f32_16x16x32_bf16(fa_l[r], fb_h[c], acc[r][c], 0, 0, 0);
        acc[r][c] = __builtin_amdgcn_mfma_f32_16x16x32_bf16(fa_h[r], fb_l[c], acc[r][c], 0, 0, 0);
      }
    __syncthreads();
  }

  // ---- C write (bf16): lane holds rows fq*4+reg, col fr of each tile
#pragma unroll
  for (int r = 0; r < 4; r++)
#pragma unroll
    for (int c = 0; c < 4; c++) {
      int colg = col0 + wc + c * 16 + fr;
#pragma unroll
      for (int reg = 0; reg < 4; reg++) {
        int gr = row0 + wr + r * 16 + fq * 4 + reg;
        if (gr < Nrows) hout[(size_t)gr * 256 + colg] = f2bf(acc[r][c][reg]);
      }
    }

  // ---- attention scores: wave's 64 cols = one head (wc 64-aligned)
  const int head = (col0 + wc) >> 6;
  float asv[4], adv[4];
#pragma unroll
  for (int c = 0; c < 4; c++) {
    asv[c] = att_s[col0 + wc + c * 16 + fr];
    adv[c] = att_d[col0 + wc + c * 16 + fr];
  }
#pragma unroll
  for (int r = 0; r < 4; r++)
#pragma unroll
    for (int reg = 0; reg < 4; reg++) {
      float ps = 0.f, pd = 0.f;
#pragma unroll
      for (int c = 0; c < 4; c++) {
        ps += acc[r][c][reg] * asv[c];
        pd += acc[r][c][reg] * adv[c];
      }
      ps += __shfl_xor(ps, 1); pd += __shfl_xor(pd, 1);
      ps += __shfl_xor(ps, 2); pd += __shfl_xor(pd, 2);
      ps += __shfl_xor(ps, 4); pd += __shfl_xor(pd, 4);
      ps += __shfl_xor(ps, 8); pd += __shfl_xor(pd, 8);
      if (fr == 0) {
        int gr = row0 + wr + r * 16 + fq * 4 + reg;
        if (gr < Nrows) {
          a_s[(size_t)gr * 4 + head] = ps;
          a_d[(size_t)gr * 4 + head] = pd;
        }
      }
    }
}

// ----------------------------- aggregation ---------------------------------
// One wave per (node, channel-half); octet mapping blockIdx%8. h gathered as
// bf16 (half the bytes of fp32). Weights inline from a_s/a_d (L2-resident),
// denominator accumulated in the j-loop.
// LAYER 1: relu(acc/den + bias) -> split bf16 (hb_h, hb_l).
// LAYER 2: acc/den -> fp32 temp (k_final mixes heads).
template <int LAYER>
__global__ __launch_bounds__(256)
void k_aggr(const ushort* __restrict__ hsrc, const int* __restrict__ rowptr,
            const int* __restrict__ col, const float* __restrict__ a_s,
            const float* __restrict__ a_d, const float* __restrict__ bias,
            ushort* __restrict__ out_h, ushort* __restrict__ out_l,
            float* __restrict__ outf, int N) {
  __shared__ int   s_sh[4][64];
  __shared__ float w_sh[4][128];
  const int wv = threadIdx.x >> 6;
  const int lane = threadIdx.x & 63;
  const int g = blockIdx.x >> 3;
  const int s8 = blockIdx.x & 7;
  const int half = s8 >> 2;
  const int node = g * 16 + (s8 & 3) * 4 + wv;
  if (node >= N) return;
  const int hd = lane >> 5;
  const int beg = rowptr[node], end = rowptr[node + 1];
  const float2 adst = *(const float2*)(a_d + (size_t)node * 4 + half * 2);

  float2 acc = make_float2(0.f, 0.f);
  float wsum = 0.f;

  for (int c0 = beg; c0 < end; c0 += 64) {
    int nc = min(64, end - c0);
    int s = 0;
    float w0 = 0.f, w1 = 0.f;
    if (lane < nc) {
      s = col[c0 + lane];
      float2 asr = *(const float2*)(a_s + (size_t)s * 4 + half * 2);
      float e0 = asr.x + adst.x; e0 = e0 > 0.f ? e0 : 0.2f * e0;
      float e1 = asr.y + adst.y; e1 = e1 > 0.f ? e1 : 0.2f * e1;
      w0 = __expf(e0); w1 = __expf(e1);
    }
    s_sh[wv][lane] = s;
    *(float2*)(&w_sh[wv][lane * 2]) = make_float2(w0, w1);
    asm volatile("s_waitcnt lgkmcnt(0)" ::: "memory");

    const float* wrow = &w_sh[wv][hd];
    const int*   srow = &s_sh[wv][0];
    const ushort* hbase = hsrc + half * 128 + lane * 2;
    int j = 0;
    for (; j + 4 <= nc; j += 4) {
      int sj0 = srow[j], sj1 = srow[j + 1], sj2 = srow[j + 2], sj3 = srow[j + 3];
      float ww0 = wrow[2 * j],     ww1 = wrow[2 * j + 2];
      float ww2 = wrow[2 * j + 4], ww3 = wrow[2 * j + 6];
      ushort2 u0 = *(const ushort2*)(hbase + (size_t)sj0 * 256);
      ushort2 u1 = *(const ushort2*)(hbase + (size_t)sj1 * 256);
      ushort2 u2 = *(const ushort2*)(hbase + (size_t)sj2 * 256);
      ushort2 u3 = *(const ushort2*)(hbase + (size_t)sj3 * 256);
      wsum += ww0 + ww1 + ww2 + ww3;
      acc.x += ww0 * bf2f(u0.x); acc.y += ww0 * bf2f(u0.y);
      acc.x += ww1 * bf2f(u1.x); acc.y += ww1 * bf2f(u1.y);
      acc.x += ww2 * bf2f(u2.x); acc.y += ww2 * bf2f(u2.y);
      acc.x += ww3 * bf2f(u3.x); acc.y += ww3 * bf2f(u3.y);
    }
    for (; j < nc; j++) {
      int sj = srow[j];
      float ww = wrow[2 * j];
      ushort2 u = *(const ushort2*)(hbase + (size_t)sj * 256);
      wsum += ww;
      acc.x += ww * bf2f(u.x); acc.y += ww * bf2f(u.y);
    }
  }

  float inv = 1.0f / wsum;  // deg>=1 via self-loop
  float2 v = make_float2(acc.x * inv, acc.y * inv);
  const size_t o = (size_t)node * 256 + half * 128 + lane * 2;
  if (LAYER == 1) {
    float2 bv = *(const float2*)(bias + half * 128 + lane * 2);
    v.x = fmaxf(v.x + bv.x, 0.f);
    v.y = fmaxf(v.y + bv.y, 0.f);
    ushort2 h, l;
    h.x = f2bf(v.x); l.x = f2bf(v.x - bf2f(h.x));
    h.y = f2bf(v.y); l.y = f2bf(v.y - bf2f(h.y));
    *(ushort2*)(out_h + o) = h;
    *(ushort2*)(out_l + o) = l;
  } else {
    *(float2*)(outf + o) = v;
  }
}

// Layer-2 epilogue: head-mean + bias + relu + softmax(64). One wave per node.
__global__ __launch_bounds__(256)
void k_final(const float* __restrict__ t, const float* __restrict__ b2,
             float* __restrict__ out, int N) {
  int node = (int)((blockIdx.x * 256u + threadIdx.x) >> 6);
  int lane = threadIdx.x & 63;
  if (node >= N) return;
  const float* tr = t + (size_t)node * 256;
  float v = 0.25f * (tr[lane] + tr[64 + lane] + tr[128 + lane] + tr[192 + lane]) + b2[lane];
  v = fmaxf(v, 0.f);
  float mx = v;
  for (int off = 32; off; off >>= 1) mx = fmaxf(mx, __shfl_xor(mx, off));
  float e = __expf(v - mx);
  float sum = e;
  for (int off = 32; off; off >>= 1) sum += __shfl_xor(sum, off);
  out[(size_t)node * 64 + lane] = e / sum;
}

// ---------------------------------------------------------------------------

extern "C" void kernel_launch(void* const* d_in, const int* in_sizes, int n_in,
                              void* d_out, int out_size, void* d_ws, size_t ws_size,
                              hipStream_t stream) {
  const float* x   = (const float*)d_in[0];
  const int*   ei  = (const int*)d_in[1];
  const float* W1  = (const float*)d_in[2];
  const float* as1 = (const float*)d_in[3];
  const float* ad1 = (const float*)d_in[4];
  const float* b1  = (const float*)d_in[5];
  const float* W2  = (const float*)d_in[6];
  const float* as2 = (const float*)d_in[7];
  const float* ad2 = (const float*)d_in[8];
  const float* b2  = (const float*)d_in[9];
  float* out = (float*)d_out;

  const int N = in_sizes[0] / 128;
  const int E = in_sizes[1] / 2;
  const int* srcv = ei;
  const int* dstv = ei + E;

  // ---- workspace layout
  ushort* h1   = (ushort*)d_ws;                   // [N,256] bf16 (also h2)
  ushort* hb_h = h1 + (size_t)N * 256;            // [N,256] bf16
  ushort* hb_l = hb_h + (size_t)N * 256;          // [N,256] bf16
  float*  temp = (float*)hb_h;                    // [N,256] fp32 (aliases hb; safe: hb dead)
  ushort* x_h  = hb_l + (size_t)N * 256;          // [N,128] bf16
  ushort* x_l  = x_h + (size_t)N * 128;           // [N,128] bf16
  ushort* w1th = x_l + (size_t)N * 128;           // [256][128] x2
  ushort* w1tl = w1th + 256 * 128;
  ushort* w2th = w1tl + 256 * 128;                // [256][256] x2
  ushort* w2tl = w2th + 256 * 256;
  float*  zbuf = (float*)(w2tl + 256 * 256);      // a_s1,a_d1,a_s2,a_d2 [16N]
  float* a_s1 = zbuf;
  float* a_d1 = a_s1 + (size_t)N * 4;
  float* a_s2 = a_d1 + (size_t)N * 4;
  float* a_d2 = a_s2 + (size_t)N * 4;
  int* rowptr = (int*)(zbuf + (size_t)N * 16);    // [N+1] (+pad)
  int* cnt    = rowptr + (N + 4);                 // [N]
  int* cursor = cnt + N;                          // [N]
  int* colx   = cursor + N;                       // [E]
  int* partials = colx + E;                       // [<=256]

  const int nb = (N + 255) / 256;
  const int eb = (E + 255) / 256;

  hipMemsetAsync(cnt, 0, (size_t)N * 4, stream);
  k_hist<<<eb, 256, 0, stream>>>(dstv, cnt, E);
  k_scan_local<<<nb, 256, 0, stream>>>(cnt, rowptr, partials, N);
  k_scan_part<<<1, 256, 0, stream>>>(partials, nb);
  k_scan_add<<<nb, 256, 0, stream>>>(rowptr, partials, cursor, N, E);
  k_scatter<<<eb, 256, 0, stream>>>(srcv, dstv, cursor, colx, E);

  k_split_x<<<(N * 128 / 4 + 255) / 256, 256, 0, stream>>>(x, x_h, x_l, N * 128 / 4);
  k_prep_w<<<128, 256, 0, stream>>>(W1, w1th, w1tl, 128);
  k_prep_w<<<256, 256, 0, stream>>>(W2, w2th, w2tl, 256);

  dim3 gg((N + 127) / 128, 2);
  const int ab = ((N + 15) / 16) * 8;  // octet-mapped (node, half) waves
  const int wb = (N + 3) / 4;          // wave-per-node

  k_gemm_mfma<<<gg, 256, 0, stream>>>(x_h, x_l, w1th, w1tl, h1, N, 128,
                                      as1, ad1, a_s1, a_d1);
  k_aggr<1><<<ab, 256, 0, stream>>>(h1, rowptr, colx, a_s1, a_d1, b1,
                                    hb_h, hb_l, nullptr, N);
  k_gemm_mfma<<<gg, 256, 0, stream>>>(hb_h, hb_l, w2th, w2tl, h1, N, 256,
                                      as2, ad2, a_s2, a_d2);
  k_aggr<2><<<ab, 256, 0, stream>>>(h1, rowptr, colx, a_s2, a_d2, b2,
                                    nullptr, nullptr, temp, N);
  k_final<<<wb, 256, 0, stream>>>(temp, b2, out, N);
}

// Round 9
// 431.656 us; speedup vs baseline: 1.4922x; 1.0317x over previous
//
#include <hip/hip_runtime.h>

// ---------------------------------------------------------------------------
// 2-layer GAT (PyG GATConv), MI355X.
// R9: k_aggr merged halves — ONE wave per node, lane owns 4 channels
//     (ushort4 gather), head = lane>>4. Halves the per-edge overhead chain
//     (R8 processed each edge twice at 34 inst/edge-half, VALUBusy 64%).
//     k_final fused into aggr<2> epilogue (head-mean shfl_xor 16/32 +
//     16-lane softmax) -> one fewer dispatch, no fp32 temp round-trip.
//     Octet XCD split dropped (R8 FETCH evidence: 189 vs ~205 MB — L2
//     evictions defeat it; not worth 2x edge processing).
//     GEMM (split-bf16 MFMA) and CSR unchanged from R8.
// ---------------------------------------------------------------------------

typedef __attribute__((ext_vector_type(8))) short short8;
typedef __attribute__((ext_vector_type(4))) float f32x4;

static __device__ __forceinline__ ushort f2bf(float f) {  // RNE
  uint u = __float_as_uint(f);
  return (ushort)((u + 0x7FFFu + ((u >> 16) & 1u)) >> 16);
}
static __device__ __forceinline__ float bf2f(ushort s) {
  return __uint_as_float(((uint)s) << 16);
}

// ----------------------------- CSR build -----------------------------------
__global__ __launch_bounds__(256)
void k_hist(const int* __restrict__ dstv, int* __restrict__ cnt, int E) {
  int i = blockIdx.x * 256 + threadIdx.x;
  if (i < E) atomicAdd(&cnt[dstv[i]], 1);
}

__global__ __launch_bounds__(256)
void k_scan_local(const int* __restrict__ cnt, int* __restrict__ rowptr,
                  int* __restrict__ partials, int N) {
  __shared__ int sm[256];
  int gid = blockIdx.x * 256 + threadIdx.x;
  int v = (gid < N) ? cnt[gid] : 0;
  sm[threadIdx.x] = v;
  __syncthreads();
  for (int off = 1; off < 256; off <<= 1) {
    int t = (threadIdx.x >= (unsigned)off) ? sm[threadIdx.x - off] : 0;
    __syncthreads();
    sm[threadIdx.x] += t;
    __syncthreads();
  }
  if (gid < N) rowptr[gid] = sm[threadIdx.x] - v;  // exclusive
  if (threadIdx.x == 255) partials[blockIdx.x] = sm[255];
}

__global__ __launch_bounds__(256)
void k_scan_part(int* __restrict__ partials, int nb) {
  __shared__ int sm[256];
  int t = threadIdx.x;
  int v = (t < nb) ? partials[t] : 0;
  sm[t] = v;
  __syncthreads();
  for (int off = 1; off < 256; off <<= 1) {
    int u = (t >= off) ? sm[t - off] : 0;
    __syncthreads();
    sm[t] += u;
    __syncthreads();
  }
  if (t < nb) partials[t] = sm[t] - v;  // exclusive
}

__global__ __launch_bounds__(256)
void k_scan_add(int* __restrict__ rowptr, const int* __restrict__ partials,
                int* __restrict__ cursor, int N, int E) {
  int gid = blockIdx.x * 256 + threadIdx.x;
  if (gid < N) {
    int rp = rowptr[gid] + partials[blockIdx.x];
    rowptr[gid] = rp;
    cursor[gid] = rp;
  }
  if (gid == 0) rowptr[N] = E;
}

__global__ __launch_bounds__(256)
void k_scatter(const int* __restrict__ srcv, const int* __restrict__ dstv,
               int* __restrict__ cursor, int* __restrict__ col, int E) {
  int i = blockIdx.x * 256 + threadIdx.x;
  if (i < E) {
    int p = atomicAdd(&cursor[dstv[i]], 1);
    col[p] = srcv[i];
  }
}

// ----------------------------- prep: splits --------------------------------
__global__ __launch_bounds__(256)
void k_split_x(const float* __restrict__ x, ushort* __restrict__ xh,
               ushort* __restrict__ xl, int total4) {
  int gid = blockIdx.x * 256 + threadIdx.x;
  if (gid >= total4) return;
  float4 v = ((const float4*)x)[gid];
  ushort4 h, l;
  h.x = f2bf(v.x); l.x = f2bf(v.x - bf2f(h.x));
  h.y = f2bf(v.y); l.y = f2bf(v.y - bf2f(h.y));
  h.z = f2bf(v.z); l.z = f2bf(v.z - bf2f(h.z));
  h.w = f2bf(v.w); l.w = f2bf(v.w - bf2f(h.w));
  ((ushort4*)xh)[gid] = h;
  ((ushort4*)xl)[gid] = l;
}

__global__ __launch_bounds__(256)
void k_prep_w(const float* __restrict__ W, ushort* __restrict__ wth,
              ushort* __restrict__ wtl, int K) {
  int gid = blockIdx.x * 256 + threadIdx.x;  // gid < K*256
  int c = gid & 255, k = gid >> 8;
  float w = W[(size_t)k * 256 + c];
  ushort h = f2bf(w);
  wth[(size_t)c * K + k] = h;
  wtl[(size_t)c * K + k] = f2bf(w - bf2f(h));
}

// ----------------------------- MFMA GEMM -----------------------------------
// C[N,256] = (Ah+Al)[N,K] @ (Bh+Bl)[K,256], Bt stored [256][K].
// Block 128x128, 4 waves 2x2, wave tile 64x64 = 4x4 MFMA 16x16x32 tiles,
// 3-term split. Output hout bf16; epilogue stores a_s/a_d (plain stores).
__global__ __launch_bounds__(256)
void k_gemm_mfma(const ushort* __restrict__ Ah, const ushort* __restrict__ Al,
                 const ushort* __restrict__ Bth, const ushort* __restrict__ Btl,
                 ushort* __restrict__ hout, int Nrows, int K,
                 const float* __restrict__ att_s, const float* __restrict__ att_d,
                 float* __restrict__ a_s, float* __restrict__ a_d) {
  __shared__ ushort As_h[128][40], As_l[128][40];
  __shared__ ushort Bs_h[128][40], Bs_l[128][40];
  const int t = threadIdx.x;
  const int lane = t & 63;
  const int w = t >> 6;
  const int wr = (w >> 1) * 64;
  const int wc = (w & 1) * 64;
  const int row0 = blockIdx.x * 128;
  const int col0 = blockIdx.y * 128;
  const int lrow = t >> 2;       // 0..63 staging index
  const int kc = (t & 3) * 8;    // k-chunk within BK=32

  f32x4 acc[4][4] = {};

  uint4 pa_h[2], pa_l[2], pb_h[2], pb_l[2];
  const uint4 z4 = make_uint4(0, 0, 0, 0);
#pragma unroll
  for (int p = 0; p < 2; p++) {
    int gr = row0 + p * 64 + lrow;
    if (gr < Nrows) {
      pa_h[p] = *(const uint4*)(Ah + (size_t)gr * K + kc);
      pa_l[p] = *(const uint4*)(Al + (size_t)gr * K + kc);
    } else { pa_h[p] = z4; pa_l[p] = z4; }
    int gc = col0 + p * 64 + lrow;
    pb_h[p] = *(const uint4*)(Bth + (size_t)gc * K + kc);
    pb_l[p] = *(const uint4*)(Btl + (size_t)gc * K + kc);
  }

  const int fr = lane & 15;
  const int fq = lane >> 4;

  for (int k0 = 0; k0 < K; k0 += 32) {
#pragma unroll
    for (int p = 0; p < 2; p++) {
      *(uint4*)(&As_h[p * 64 + lrow][kc]) = pa_h[p];
      *(uint4*)(&As_l[p * 64 + lrow][kc]) = pa_l[p];
      *(uint4*)(&Bs_h[p * 64 + lrow][kc]) = pb_h[p];
      *(uint4*)(&Bs_l[p * 64 + lrow][kc]) = pb_l[p];
    }
    __syncthreads();

    if (k0 + 32 < K) {
#pragma unroll
      for (int p = 0; p < 2; p++) {
        int gr = row0 + p * 64 + lrow;
        if (gr < Nrows) {
          pa_h[p] = *(const uint4*)(Ah + (size_t)gr * K + k0 + 32 + kc);
          pa_l[p] = *(const uint4*)(Al + (size_t)gr * K + k0 + 32 + kc);
        } else { pa_h[p] = z4; pa_l[p] = z4; }
        int gc = col0 + p * 64 + lrow;
        pb_h[p] = *(const uint4*)(Bth + (size_t)gc * K + k0 + 32 + kc);
        pb_l[p] = *(const uint4*)(Btl + (size_t)gc * K + k0 + 32 + kc);
      }
    }

    short8 fa_h[4], fa_l[4], fb_h[4], fb_l[4];
#pragma unroll
    for (int r = 0; r < 4; r++) {
      fa_h[r] = *(const short8*)(&As_h[wr + r * 16 + fr][fq * 8]);
      fa_l[r] = *(const short8*)(&As_l[wr + r * 16 + fr][fq * 8]);
    }
#pragma unroll
    for (int c = 0; c < 4; c++) {
      fb_h[c] = *(const short8*)(&Bs_h[wc + c * 16 + fr][fq * 8]);
      fb_l[c] = *(const short8*)(&Bs_l[wc + c * 16 + fr][fq * 8]);
    }
#pragma unroll
    for (int r = 0; r < 4; r++)
#pragma unroll
      for (int c = 0; c < 4; c++) {
        acc[r][c] = __builtin_amdgcn_mfma_f32_16x16x32_bf16(fa_h[r], fb_h[c], acc[r][c], 0, 0, 0);
        acc[r][c] = __builtin_amdgcn_mfma_f32_16x16x32_bf16(fa_l[r], fb_h[c], acc[r][c], 0, 0, 0);
        acc[r][c] = __builtin_amdgcn_mfma_f32_16x16x32_bf16(fa_h[r], fb_l[c], acc[r][c], 0, 0, 0);
      }
    __syncthreads();
  }

  // ---- C write (bf16)
#pragma unroll
  for (int r = 0; r < 4; r++)
#pragma unroll
    for (int c = 0; c < 4; c++) {
      int colg = col0 + wc + c * 16 + fr;
#pragma unroll
      for (int reg = 0; reg < 4; reg++) {
        int gr = row0 + wr + r * 16 + fq * 4 + reg;
        if (gr < Nrows) hout[(size_t)gr * 256 + colg] = f2bf(acc[r][c][reg]);
      }
    }

  // ---- attention scores: wave's 64 cols = one head (wc 64-aligned)
  const int head = (col0 + wc) >> 6;
  float asv[4], adv[4];
#pragma unroll
  for (int c = 0; c < 4; c++) {
    asv[c] = att_s[col0 + wc + c * 16 + fr];
    adv[c] = att_d[col0 + wc + c * 16 + fr];
  }
#pragma unroll
  for (int r = 0; r < 4; r++)
#pragma unroll
    for (int reg = 0; reg < 4; reg++) {
      float ps = 0.f, pd = 0.f;
#pragma unroll
      for (int c = 0; c < 4; c++) {
        ps += acc[r][c][reg] * asv[c];
        pd += acc[r][c][reg] * adv[c];
      }
      ps += __shfl_xor(ps, 1); pd += __shfl_xor(pd, 1);
      ps += __shfl_xor(ps, 2); pd += __shfl_xor(pd, 2);
      ps += __shfl_xor(ps, 4); pd += __shfl_xor(pd, 4);
      ps += __shfl_xor(ps, 8); pd += __shfl_xor(pd, 8);
      if (fr == 0) {
        int gr = row0 + wr + r * 16 + fq * 4 + reg;
        if (gr < Nrows) {
          a_s[(size_t)gr * 4 + head] = ps;
          a_d[(size_t)gr * 4 + head] = pd;
        }
      }
    }
}

// ----------------------------- aggregation ---------------------------------
// ONE wave per node; lane owns channels [4*lane, 4*lane+3] (ushort4 gather),
// head = lane>>4. Chunk of 64 edges: lane gathers a_s[col] float4, computes
// all-head weights inline, stages (src, w[4]) in LDS. j-loop: 2 LDS reads +
// one 8B coalesced gather + 4 cnv + 4 FMA per edge. Denominator free.
// LAYER 1: relu(acc/den + bias) -> split bf16 (out_h, out_l).
// LAYER 2: fused finale — head-mean (shfl_xor 16/32) + bias + relu +
//          softmax(64) on 16 lanes -> outp [N,64] (the kernel output).
template <int LAYER>
__global__ __launch_bounds__(256)
void k_aggr(const ushort* __restrict__ hsrc, const int* __restrict__ rowptr,
            const int* __restrict__ col, const float* __restrict__ a_s,
            const float* __restrict__ a_d, const float* __restrict__ bias,
            ushort* __restrict__ out_h, ushort* __restrict__ out_l,
            float* __restrict__ outp, int N) {
  __shared__ int   s_sh[4][64];
  __shared__ float w_sh[4][256];
  const int wv = threadIdx.x >> 6;
  const int lane = threadIdx.x & 63;
  const int node = blockIdx.x * 4 + wv;
  if (node >= N) return;
  const int hd = lane >> 4;
  const int beg = rowptr[node], end = rowptr[node + 1];
  const float4 adst = *(const float4*)(a_d + (size_t)node * 4);

  float4 acc = make_float4(0.f, 0.f, 0.f, 0.f);
  float wsum = 0.f;
  const char* hbase = (const char*)(hsrc + lane * 4);

  for (int c0 = beg; c0 < end; c0 += 64) {
    int nc = min(64, end - c0);
    int s = 0;
    float4 w4 = make_float4(0.f, 0.f, 0.f, 0.f);
    if (lane < nc) {
      s = col[c0 + lane];
      float4 a = *(const float4*)(a_s + (size_t)s * 4);
      float e0 = a.x + adst.x; e0 = e0 > 0.f ? e0 : 0.2f * e0;
      float e1 = a.y + adst.y; e1 = e1 > 0.f ? e1 : 0.2f * e1;
      float e2 = a.z + adst.z; e2 = e2 > 0.f ? e2 : 0.2f * e2;
      float e3 = a.w + adst.w; e3 = e3 > 0.f ? e3 : 0.2f * e3;
      w4 = make_float4(__expf(e0), __expf(e1), __expf(e2), __expf(e3));
    }
    s_sh[wv][lane] = s;
    *(float4*)(&w_sh[wv][lane * 4]) = w4;
    asm volatile("s_waitcnt lgkmcnt(0)" ::: "memory");

    const float* wrow = &w_sh[wv][hd];
    const int*   srow = &s_sh[wv][0];
    int j = 0;
    for (; j + 4 <= nc; j += 4) {
      int sj0 = srow[j], sj1 = srow[j + 1], sj2 = srow[j + 2], sj3 = srow[j + 3];
      float w0 = wrow[4 * j],      w1 = wrow[4 * j + 4];
      float w2 = wrow[4 * j + 8],  w3 = wrow[4 * j + 12];
      ushort4 u0 = *(const ushort4*)(hbase + ((size_t)((uint)sj0 << 9)));
      ushort4 u1 = *(const ushort4*)(hbase + ((size_t)((uint)sj1 << 9)));
      ushort4 u2 = *(const ushort4*)(hbase + ((size_t)((uint)sj2 << 9)));
      ushort4 u3 = *(const ushort4*)(hbase + ((size_t)((uint)sj3 << 9)));
      wsum += w0 + w1 + w2 + w3;
      acc.x += w0 * bf2f(u0.x); acc.y += w0 * bf2f(u0.y);
      acc.z += w0 * bf2f(u0.z); acc.w += w0 * bf2f(u0.w);
      acc.x += w1 * bf2f(u1.x); acc.y += w1 * bf2f(u1.y);
      acc.z += w1 * bf2f(u1.z); acc.w += w1 * bf2f(u1.w);
      acc.x += w2 * bf2f(u2.x); acc.y += w2 * bf2f(u2.y);
      acc.z += w2 * bf2f(u2.z); acc.w += w2 * bf2f(u2.w);
      acc.x += w3 * bf2f(u3.x); acc.y += w3 * bf2f(u3.y);
      acc.z += w3 * bf2f(u3.z); acc.w += w3 * bf2f(u3.w);
    }
    for (; j < nc; j++) {
      int sj = srow[j];
      float ww = wrow[4 * j];
      ushort4 u = *(const ushort4*)(hbase + ((size_t)((uint)sj << 9)));
      wsum += ww;
      acc.x += ww * bf2f(u.x); acc.y += ww * bf2f(u.y);
      acc.z += ww * bf2f(u.z); acc.w += ww * bf2f(u.w);
    }
  }

  float inv = 1.0f / wsum;  // deg>=1 via self-loop
  float4 v = make_float4(acc.x * inv, acc.y * inv, acc.z * inv, acc.w * inv);

  if (LAYER == 1) {
    const float4 bv = *(const float4*)(bias + lane * 4);
    v.x = fmaxf(v.x + bv.x, 0.f);
    v.y = fmaxf(v.y + bv.y, 0.f);
    v.z = fmaxf(v.z + bv.z, 0.f);
    v.w = fmaxf(v.w + bv.w, 0.f);
    ushort4 h, l;
    h.x = f2bf(v.x); l.x = f2bf(v.x - bf2f(h.x));
    h.y = f2bf(v.y); l.y = f2bf(v.y - bf2f(h.y));
    h.z = f2bf(v.z); l.z = f2bf(v.z - bf2f(h.z));
    h.w = f2bf(v.w); l.w = f2bf(v.w - bf2f(h.w));
    const size_t o = (size_t)node * 256 + lane * 4;
    *(ushort4*)(out_h + o) = h;
    *(ushort4*)(out_l + o) = l;
  } else {
    // fused finale: head-mean + bias + relu + softmax(64)
    v.x += __shfl_xor(v.x, 16); v.y += __shfl_xor(v.y, 16);
    v.z += __shfl_xor(v.z, 16); v.w += __shfl_xor(v.w, 16);
    v.x += __shfl_xor(v.x, 32); v.y += __shfl_xor(v.y, 32);
    v.z += __shfl_xor(v.z, 32); v.w += __shfl_xor(v.w, 32);
    const int c4 = (lane & 15) * 4;
    const float4 bv = *(const float4*)(bias + c4);
    v.x = fmaxf(v.x * 0.25f + bv.x, 0.f);
    v.y = fmaxf(v.y * 0.25f + bv.y, 0.f);
    v.z = fmaxf(v.z * 0.25f + bv.z, 0.f);
    v.w = fmaxf(v.w * 0.25f + bv.w, 0.f);
    float mx = fmaxf(fmaxf(v.x, v.y), fmaxf(v.z, v.w));
    for (int off = 8; off >= 1; off >>= 1) mx = fmaxf(mx, __shfl_xor(mx, off));
    v.x = __expf(v.x - mx); v.y = __expf(v.y - mx);
    v.z = __expf(v.z - mx); v.w = __expf(v.w - mx);
    float sum = v.x + v.y + v.z + v.w;
    for (int off = 8; off >= 1; off >>= 1) sum += __shfl_xor(sum, off);
    float is = 1.0f / sum;
    v.x *= is; v.y *= is; v.z *= is; v.w *= is;
    if (lane < 16) *(float4*)(outp + (size_t)node * 64 + c4) = v;
  }
}

// ---------------------------------------------------------------------------

extern "C" void kernel_launch(void* const* d_in, const int* in_sizes, int n_in,
                              void* d_out, int out_size, void* d_ws, size_t ws_size,
                              hipStream_t stream) {
  const float* x   = (const float*)d_in[0];
  const int*   ei  = (const int*)d_in[1];
  const float* W1  = (const float*)d_in[2];
  const float* as1 = (const float*)d_in[3];
  const float* ad1 = (const float*)d_in[4];
  const float* b1  = (const float*)d_in[5];
  const float* W2  = (const float*)d_in[6];
  const float* as2 = (const float*)d_in[7];
  const float* ad2 = (const float*)d_in[8];
  const float* b2  = (const float*)d_in[9];
  float* out = (float*)d_out;

  const int N = in_sizes[0] / 128;
  const int E = in_sizes[1] / 2;
  const int* srcv = ei;
  const int* dstv = ei + E;

  // ---- workspace layout
  ushort* h1   = (ushort*)d_ws;                   // [N,256] bf16 (also h2)
  ushort* hb_h = h1 + (size_t)N * 256;            // [N,256] bf16
  ushort* hb_l = hb_h + (size_t)N * 256;          // [N,256] bf16
  ushort* x_h  = hb_l + (size_t)N * 256;          // [N,128] bf16
  ushort* x_l  = x_h + (size_t)N * 128;           // [N,128] bf16
  ushort* w1th = x_l + (size_t)N * 128;           // [256][128] x2
  ushort* w1tl = w1th + 256 * 128;
  ushort* w2th = w1tl + 256 * 128;                // [256][256] x2
  ushort* w2tl = w2th + 256 * 256;
  float*  zbuf = (float*)(w2tl + 256 * 256);      // a_s1,a_d1,a_s2,a_d2 [16N]
  float* a_s1 = zbuf;
  float* a_d1 = a_s1 + (size_t)N * 4;
  float* a_s2 = a_d1 + (size_t)N * 4;
  float* a_d2 = a_s2 + (size_t)N * 4;
  int* rowptr = (int*)(zbuf + (size_t)N * 16);    // [N+1] (+pad)
  int* cnt    = rowptr + (N + 4);                 // [N]
  int* cursor = cnt + N;                          // [N]
  int* colx   = cursor + N;                       // [E]
  int* partials = colx + E;                       // [<=256]

  const int nb = (N + 255) / 256;
  const int eb = (E + 255) / 256;

  hipMemsetAsync(cnt, 0, (size_t)N * 4, stream);
  k_hist<<<eb, 256, 0, stream>>>(dstv, cnt, E);
  k_scan_local<<<nb, 256, 0, stream>>>(cnt, rowptr, partials, N);
  k_scan_part<<<1, 256, 0, stream>>>(partials, nb);
  k_scan_add<<<nb, 256, 0, stream>>>(rowptr, partials, cursor, N, E);
  k_scatter<<<eb, 256, 0, stream>>>(srcv, dstv, cursor, colx, E);

  k_split_x<<<(N * 128 / 4 + 255) / 256, 256, 0, stream>>>(x, x_h, x_l, N * 128 / 4);
  k_prep_w<<<128, 256, 0, stream>>>(W1, w1th, w1tl, 128);
  k_prep_w<<<256, 256, 0, stream>>>(W2, w2th, w2tl, 256);

  dim3 gg((N + 127) / 128, 2);
  const int wb = (N + 3) / 4;  // one wave per node

  k_gemm_mfma<<<gg, 256, 0, stream>>>(x_h, x_l, w1th, w1tl, h1, N, 128,
                                      as1, ad1, a_s1, a_d1);
  k_aggr<1><<<wb, 256, 0, stream>>>(h1, rowptr, colx, a_s1, a_d1, b1,
                                    hb_h, hb_l, nullptr, N);
  k_gemm_mfma<<<gg, 256, 0, stream>>>(hb_h, hb_l, w2th, w2tl, h1, N, 256,
                                      as2, ad2, a_s2, a_d2);
  k_aggr<2><<<wb, 256, 0, stream>>>(h1, rowptr, colx, a_s2, a_d2, b2,
                                    nullptr, nullptr, out, N);
}

// Round 10
// 426.053 us; speedup vs baseline: 1.5119x; 1.0131x over previous
//
#include <hip/hip_runtime.h>

// ---------------------------------------------------------------------------
// 2-layer GAT (PyG GATConv), MI355X.
// R10: k_gemm_mfma memory-traffic fixes (R9: 215MB HBM/dispatch @3TB/s):
//   (a) C-write via LDS round-trip -> row-major short8 stores (R9 wrote 2B
//       scatter in MFMA C-layout -> 112MB write, ~4x RMW amplification).
//   (b) grid transposed to (colhalf, rows): the 2 col-half blocks sharing A
//       rows are dispatch-adjacent -> A's 2nd read hits L2 (R9: 391 blocks
//       apart -> A fetched twice, 97MB).
//   aggr (one-wave-per-node, fused finale) and CSR unchanged from R9.
// ---------------------------------------------------------------------------

typedef __attribute__((ext_vector_type(8))) short short8;
typedef __attribute__((ext_vector_type(4))) float f32x4;

static __device__ __forceinline__ ushort f2bf(float f) {  // RNE
  uint u = __float_as_uint(f);
  return (ushort)((u + 0x7FFFu + ((u >> 16) & 1u)) >> 16);
}
static __device__ __forceinline__ float bf2f(ushort s) {
  return __uint_as_float(((uint)s) << 16);
}

// ----------------------------- CSR build -----------------------------------
__global__ __launch_bounds__(256)
void k_hist(const int* __restrict__ dstv, int* __restrict__ cnt, int E) {
  int i = blockIdx.x * 256 + threadIdx.x;
  if (i < E) atomicAdd(&cnt[dstv[i]], 1);
}

__global__ __launch_bounds__(256)
void k_scan_local(const int* __restrict__ cnt, int* __restrict__ rowptr,
                  int* __restrict__ partials, int N) {
  __shared__ int sm[256];
  int gid = blockIdx.x * 256 + threadIdx.x;
  int v = (gid < N) ? cnt[gid] : 0;
  sm[threadIdx.x] = v;
  __syncthreads();
  for (int off = 1; off < 256; off <<= 1) {
    int t = (threadIdx.x >= (unsigned)off) ? sm[threadIdx.x - off] : 0;
    __syncthreads();
    sm[threadIdx.x] += t;
    __syncthreads();
  }
  if (gid < N) rowptr[gid] = sm[threadIdx.x] - v;  // exclusive
  if (threadIdx.x == 255) partials[blockIdx.x] = sm[255];
}

__global__ __launch_bounds__(256)
void k_scan_part(int* __restrict__ partials, int nb) {
  __shared__ int sm[256];
  int t = threadIdx.x;
  int v = (t < nb) ? partials[t] : 0;
  sm[t] = v;
  __syncthreads();
  for (int off = 1; off < 256; off <<= 1) {
    int u = (t >= off) ? sm[t - off] : 0;
    __syncthreads();
    sm[t] += u;
    __syncthreads();
  }
  if (t < nb) partials[t] = sm[t] - v;  // exclusive
}

__global__ __launch_bounds__(256)
void k_scan_add(int* __restrict__ rowptr, const int* __restrict__ partials,
                int* __restrict__ cursor, int N, int E) {
  int gid = blockIdx.x * 256 + threadIdx.x;
  if (gid < N) {
    int rp = rowptr[gid] + partials[blockIdx.x];
    rowptr[gid] = rp;
    cursor[gid] = rp;
  }
  if (gid == 0) rowptr[N] = E;
}

__global__ __launch_bounds__(256)
void k_scatter(const int* __restrict__ srcv, const int* __restrict__ dstv,
               int* __restrict__ cursor, int* __restrict__ col, int E) {
  int i = blockIdx.x * 256 + threadIdx.x;
  if (i < E) {
    int p = atomicAdd(&cursor[dstv[i]], 1);
    col[p] = srcv[i];
  }
}

// ----------------------------- prep: splits --------------------------------
__global__ __launch_bounds__(256)
void k_split_x(const float* __restrict__ x, ushort* __restrict__ xh,
               ushort* __restrict__ xl, int total4) {
  int gid = blockIdx.x * 256 + threadIdx.x;
  if (gid >= total4) return;
  float4 v = ((const float4*)x)[gid];
  ushort4 h, l;
  h.x = f2bf(v.x); l.x = f2bf(v.x - bf2f(h.x));
  h.y = f2bf(v.y); l.y = f2bf(v.y - bf2f(h.y));
  h.z = f2bf(v.z); l.z = f2bf(v.z - bf2f(h.z));
  h.w = f2bf(v.w); l.w = f2bf(v.w - bf2f(h.w));
  ((ushort4*)xh)[gid] = h;
  ((ushort4*)xl)[gid] = l;
}

__global__ __launch_bounds__(256)
void k_prep_w(const float* __restrict__ W, ushort* __restrict__ wth,
              ushort* __restrict__ wtl, int K) {
  int gid = blockIdx.x * 256 + threadIdx.x;  // gid < K*256
  int c = gid & 255, k = gid >> 8;
  float w = W[(size_t)k * 256 + c];
  ushort h = f2bf(w);
  wth[(size_t)c * K + k] = h;
  wtl[(size_t)c * K + k] = f2bf(w - bf2f(h));
}

// ----------------------------- MFMA GEMM -----------------------------------
// C[N,256] = (Ah+Al)[N,K] @ (Bh+Bl)[K,256], Bt stored [256][K].
// grid(2, rowblocks): blockIdx.x = col half (dispatch-adjacent halves share
// A rows via L2), blockIdx.y = row block. Block 128x128, 4 waves 2x2,
// wave tile 64x64 = 4x4 MFMA 16x16x32 tiles, 3-term split-bf16.
// Epilogue: per-wave LDS transpose of the 64x64 tile -> row-major short8
// stores (fully coalesced); a_s/a_d from fp32 accs (plain stores).
__global__ __launch_bounds__(256)
void k_gemm_mfma(const ushort* __restrict__ Ah, const ushort* __restrict__ Al,
                 const ushort* __restrict__ Bth, const ushort* __restrict__ Btl,
                 ushort* __restrict__ hout, int Nrows, int K,
                 const float* __restrict__ att_s, const float* __restrict__ att_d,
                 float* __restrict__ a_s, float* __restrict__ a_d) {
  __shared__ ushort smem[4 * 128 * 40];  // As_h | As_l | Bs_h | Bs_l (K-loop)
                                         // reused post-loop: 4x 64x68 C tiles
  ushort* As_h = smem;
  ushort* As_l = smem + 128 * 40;
  ushort* Bs_h = smem + 2 * 128 * 40;
  ushort* Bs_l = smem + 3 * 128 * 40;

  const int t = threadIdx.x;
  const int lane = t & 63;
  const int w = t >> 6;
  const int wr = (w >> 1) * 64;
  const int wc = (w & 1) * 64;
  const int row0 = blockIdx.y * 128;
  const int col0 = blockIdx.x * 128;
  const int lrow = t >> 2;       // 0..63 staging index
  const int kc = (t & 3) * 8;    // k-chunk within BK=32

  f32x4 acc[4][4] = {};

  uint4 pa_h[2], pa_l[2], pb_h[2], pb_l[2];
  const uint4 z4 = make_uint4(0, 0, 0, 0);
#pragma unroll
  for (int p = 0; p < 2; p++) {
    int gr = row0 + p * 64 + lrow;
    if (gr < Nrows) {
      pa_h[p] = *(const uint4*)(Ah + (size_t)gr * K + kc);
      pa_l[p] = *(const uint4*)(Al + (size_t)gr * K + kc);
    } else { pa_h[p] = z4; pa_l[p] = z4; }
    int gc = col0 + p * 64 + lrow;
    pb_h[p] = *(const uint4*)(Bth + (size_t)gc * K + kc);
    pb_l[p] = *(const uint4*)(Btl + (size_t)gc * K + kc);
  }

  const int fr = lane & 15;
  const int fq = lane >> 4;

  for (int k0 = 0; k0 < K; k0 += 32) {
#pragma unroll
    for (int p = 0; p < 2; p++) {
      *(uint4*)(&As_h[(p * 64 + lrow) * 40 + kc]) = pa_h[p];
      *(uint4*)(&As_l[(p * 64 + lrow) * 40 + kc]) = pa_l[p];
      *(uint4*)(&Bs_h[(p * 64 + lrow) * 40 + kc]) = pb_h[p];
      *(uint4*)(&Bs_l[(p * 64 + lrow) * 40 + kc]) = pb_l[p];
    }
    __syncthreads();

    if (k0 + 32 < K) {
#pragma unroll
      for (int p = 0; p < 2; p++) {
        int gr = row0 + p * 64 + lrow;
        if (gr < Nrows) {
          pa_h[p] = *(const uint4*)(Ah + (size_t)gr * K + k0 + 32 + kc);
          pa_l[p] = *(const uint4*)(Al + (size_t)gr * K + k0 + 32 + kc);
        } else { pa_h[p] = z4; pa_l[p] = z4; }
        int gc = col0 + p * 64 + lrow;
        pb_h[p] = *(const uint4*)(Bth + (size_t)gc * K + k0 + 32 + kc);
        pb_l[p] = *(const uint4*)(Btl + (size_t)gc * K + k0 + 32 + kc);
      }
    }

    short8 fa_h[4], fa_l[4], fb_h[4], fb_l[4];
#pragma unroll
    for (int r = 0; r < 4; r++) {
      fa_h[r] = *(const short8*)(&As_h[(wr + r * 16 + fr) * 40 + fq * 8]);
      fa_l[r] = *(const short8*)(&As_l[(wr + r * 16 + fr) * 40 + fq * 8]);
    }
#pragma unroll
    for (int c = 0; c < 4; c++) {
      fb_h[c] = *(const short8*)(&Bs_h[(wc + c * 16 + fr) * 40 + fq * 8]);
      fb_l[c] = *(const short8*)(&Bs_l[(wc + c * 16 + fr) * 40 + fq * 8]);
    }
#pragma unroll
    for (int r = 0; r < 4; r++)
#pragma unroll
      for (int c = 0; c < 4; c++) {
        acc[r][c] = __builtin_amdgcn_mfma_f32_16x16x32_bf16(fa_h[r], fb_h[c], acc[r][c], 0, 0, 0);
        acc[r][c] = __builtin_amdgcn_mfma_f32_16x16x32_bf16(fa_l[r], fb_h[c], acc[r][c], 0, 0, 0);
        acc[r][c] = __builtin_amdgcn_mfma_f32_16x16x32_bf16(fa_h[r], fb_l[c], acc[r][c], 0, 0, 0);
      }
    __syncthreads();
  }

  // ---- C write: wave-private LDS transpose -> coalesced row-major stores.
  // After the loop's final barrier all waves are done with the staging LDS.
  {
    ushort* tile = smem + w * (64 * 68);  // 64 rows x 68 (pad) per wave
#pragma unroll
    for (int r = 0; r < 4; r++)
#pragma unroll
      for (int c = 0; c < 4; c++)
#pragma unroll
        for (int reg = 0; reg < 4; reg++)
          tile[(r * 16 + fq * 4 + reg) * 68 + c * 16 + fr] = f2bf(acc[r][c][reg]);
    // wave-private region: ds ordering within the wave is handled by lgkmcnt
    const int rr = lane >> 3;        // 0..7
    const int cc = (lane & 7) * 8;   // 0..56
#pragma unroll
    for (int i = 0; i < 8; i++) {
      int row = i * 8 + rr;
      int gr = row0 + wr + row;
      if (gr < Nrows) {
        short8 v = *(const short8*)(&tile[row * 68 + cc]);
        *(short8*)(&hout[(size_t)gr * 256 + col0 + wc + cc]) = v;
      }
    }
  }

  // ---- attention scores: wave's 64 cols = one head (wc 64-aligned)
  const int head = (col0 + wc) >> 6;
  float asv[4], adv[4];
#pragma unroll
  for (int c = 0; c < 4; c++) {
    asv[c] = att_s[col0 + wc + c * 16 + fr];
    adv[c] = att_d[col0 + wc + c * 16 + fr];
  }
#pragma unroll
  for (int r = 0; r < 4; r++)
#pragma unroll
    for (int reg = 0; reg < 4; reg++) {
      float ps = 0.f, pd = 0.f;
#pragma unroll
      for (int c = 0; c < 4; c++) {
        ps += acc[r][c][reg] * asv[c];
        pd += acc[r][c][reg] * adv[c];
      }
      ps += __shfl_xor(ps, 1); pd += __shfl_xor(pd, 1);
      ps += __shfl_xor(ps, 2); pd += __shfl_xor(pd, 2);
      ps += __shfl_xor(ps, 4); pd += __shfl_xor(pd, 4);
      ps += __shfl_xor(ps, 8); pd += __shfl_xor(pd, 8);
      if (fr == 0) {
        int gr = row0 + wr + r * 16 + fq * 4 + reg;
        if (gr < Nrows) {
          a_s[(size_t)gr * 4 + head] = ps;
          a_d[(size_t)gr * 4 + head] = pd;
        }
      }
    }
}

// ----------------------------- aggregation ---------------------------------
// ONE wave per node; lane owns channels [4*lane, 4*lane+3] (ushort4 gather),
// head = lane>>4. Chunk of 64 edges: lane gathers a_s[col] float4, computes
// all-head weights inline, stages (src, w[4]) in LDS. Denominator free.
// LAYER 1: relu(acc/den + bias) -> split bf16 (out_h, out_l).
// LAYER 2: fused finale — head-mean + bias + relu + softmax(64) -> outp.
template <int LAYER>
__global__ __launch_bounds__(256)
void k_aggr(const ushort* __restrict__ hsrc, const int* __restrict__ rowptr,
            const int* __restrict__ col, const float* __restrict__ a_s,
            const float* __restrict__ a_d, const float* __restrict__ bias,
            ushort* __restrict__ out_h, ushort* __restrict__ out_l,
            float* __restrict__ outp, int N) {
  __shared__ int   s_sh[4][64];
  __shared__ float w_sh[4][256];
  const int wv = threadIdx.x >> 6;
  const int lane = threadIdx.x & 63;
  const int node = blockIdx.x * 4 + wv;
  if (node >= N) return;
  const int hd = lane >> 4;
  const int beg = rowptr[node], end = rowptr[node + 1];
  const float4 adst = *(const float4*)(a_d + (size_t)node * 4);

  float4 acc = make_float4(0.f, 0.f, 0.f, 0.f);
  float wsum = 0.f;
  const char* hbase = (const char*)(hsrc + lane * 4);

  for (int c0 = beg; c0 < end; c0 += 64) {
    int nc = min(64, end - c0);
    int s = 0;
    float4 w4 = make_float4(0.f, 0.f, 0.f, 0.f);
    if (lane < nc) {
      s = col[c0 + lane];
      float4 a = *(const float4*)(a_s + (size_t)s * 4);
      float e0 = a.x + adst.x; e0 = e0 > 0.f ? e0 : 0.2f * e0;
      float e1 = a.y + adst.y; e1 = e1 > 0.f ? e1 : 0.2f * e1;
      float e2 = a.z + adst.z; e2 = e2 > 0.f ? e2 : 0.2f * e2;
      float e3 = a.w + adst.w; e3 = e3 > 0.f ? e3 : 0.2f * e3;
      w4 = make_float4(__expf(e0), __expf(e1), __expf(e2), __expf(e3));
    }
    s_sh[wv][lane] = s;
    *(float4*)(&w_sh[wv][lane * 4]) = w4;
    asm volatile("s_waitcnt lgkmcnt(0)" ::: "memory");

    const float* wrow = &w_sh[wv][hd];
    const int*   srow = &s_sh[wv][0];
    int j = 0;
    for (; j + 4 <= nc; j += 4) {
      int sj0 = srow[j], sj1 = srow[j + 1], sj2 = srow[j + 2], sj3 = srow[j + 3];
      float w0 = wrow[4 * j],      w1 = wrow[4 * j + 4];
      float w2 = wrow[4 * j + 8],  w3 = wrow[4 * j + 12];
      ushort4 u0 = *(const ushort4*)(hbase + ((size_t)((uint)sj0 << 9)));
      ushort4 u1 = *(const ushort4*)(hbase + ((size_t)((uint)sj1 << 9)));
      ushort4 u2 = *(const ushort4*)(hbase + ((size_t)((uint)sj2 << 9)));
      ushort4 u3 = *(const ushort4*)(hbase + ((size_t)((uint)sj3 << 9)));
      wsum += w0 + w1 + w2 + w3;
      acc.x += w0 * bf2f(u0.x); acc.y += w0 * bf2f(u0.y);
      acc.z += w0 * bf2f(u0.z); acc.w += w0 * bf2f(u0.w);
      acc.x += w1 * bf2f(u1.x); acc.y += w1 * bf2f(u1.y);
      acc.z += w1 * bf2f(u1.z); acc.w += w1 * bf2f(u1.w);
      acc.x += w2 * bf2f(u2.x); acc.y += w2 * bf2f(u2.y);
      acc.z += w2 * bf2f(u2.z); acc.w += w2 * bf2f(u2.w);
      acc.x += w3 * bf2f(u3.x); acc.y += w3 * bf2f(u3.y);
      acc.z += w3 * bf2f(u3.z); acc.w += w3 * bf2f(u3.w);
    }
    for (; j < nc; j++) {
      int sj = srow[j];
      float ww = wrow[4 * j];
      ushort4 u = *(const ushort4*)(hbase + ((size_t)((uint)sj << 9)));
      wsum += ww;
      acc.x += ww * bf2f(u.x); acc.y += ww * bf2f(u.y);
      acc.z += ww * bf2f(u.z); acc.w += ww * bf2f(u.w);
    }
  }

  float inv = 1.0f / wsum;  // deg>=1 via self-loop
  float4 v = make_float4(acc.x * inv, acc.y * inv, acc.z * inv, acc.w * inv);

  if (LAYER == 1) {
    const float4 bv = *(const float4*)(bias + lane * 4);
    v.x = fmaxf(v.x + bv.x, 0.f);
    v.y = fmaxf(v.y + bv.y, 0.f);
    v.z = fmaxf(v.z + bv.z, 0.f);
    v.w = fmaxf(v.w + bv.w, 0.f);
    ushort4 h, l;
    h.x = f2bf(v.x); l.x = f2bf(v.x - bf2f(h.x));
    h.y = f2bf(v.y); l.y = f2bf(v.y - bf2f(h.y));
    h.z = f2bf(v.z); l.z = f2bf(v.z - bf2f(h.z));
    h.w = f2bf(v.w); l.w = f2bf(v.w - bf2f(h.w));
    const size_t o = (size_t)node * 256 + lane * 4;
    *(ushort4*)(out_h + o) = h;
    *(ushort4*)(out_l + o) = l;
  } else {
    // fused finale: head-mean + bias + relu + softmax(64)
    v.x += __shfl_xor(v.x, 16); v.y += __shfl_xor(v.y, 16);
    v.z += __shfl_xor(v.z, 16); v.w += __shfl_xor(v.w, 16);
    v.x += __shfl_xor(v.x, 32); v.y += __shfl_xor(v.y, 32);
    v.z += __shfl_xor(v.z, 32); v.w += __shfl_xor(v.w, 32);
    const int c4 = (lane & 15) * 4;
    const float4 bv = *(const float4*)(bias + c4);
    v.x = fmaxf(v.x * 0.25f + bv.x, 0.f);
    v.y = fmaxf(v.y * 0.25f + bv.y, 0.f);
    v.z = fmaxf(v.z * 0.25f + bv.z, 0.f);
    v.w = fmaxf(v.w * 0.25f + bv.w, 0.f);
    float mx = fmaxf(fmaxf(v.x, v.y), fmaxf(v.z, v.w));
    for (int off = 8; off >= 1; off >>= 1) mx = fmaxf(mx, __shfl_xor(mx, off));
    v.x = __expf(v.x - mx); v.y = __expf(v.y - mx);
    v.z = __expf(v.z - mx); v.w = __expf(v.w - mx);
    float sum = v.x + v.y + v.z + v.w;
    for (int off = 8; off >= 1; off >>= 1) sum += __shfl_xor(sum, off);
    float is = 1.0f / sum;
    v.x *= is; v.y *= is; v.z *= is; v.w *= is;
    if (lane < 16) *(float4*)(outp + (size_t)node * 64 + c4) = v;
  }
}

// ---------------------------------------------------------------------------

extern "C" void kernel_launch(void* const* d_in, const int* in_sizes, int n_in,
                              void* d_out, int out_size, void* d_ws, size_t ws_size,
                              hipStream_t stream) {
  const float* x   = (const float*)d_in[0];
  const int*   ei  = (const int*)d_in[1];
  const float* W1  = (const float*)d_in[2];
  const float* as1 = (const float*)d_in[3];
  const float* ad1 = (const float*)d_in[4];
  const float* b1  = (const float*)d_in[5];
  const float* W2  = (const float*)d_in[6];
  const float* as2 = (const float*)d_in[7];
  const float* ad2 = (const float*)d_in[8];
  const float* b2  = (const float*)d_in[9];
  float* out = (float*)d_out;

  const int N = in_sizes[0] / 128;
  const int E = in_sizes[1] / 2;
  const int* srcv = ei;
  const int* dstv = ei + E;

  // ---- workspace layout
  ushort* h1   = (ushort*)d_ws;                   // [N,256] bf16 (also h2)
  ushort* hb_h = h1 + (size_t)N * 256;            // [N,256] bf16
  ushort* hb_l = hb_h + (size_t)N * 256;          // [N,256] bf16
  ushort* x_h  = hb_l + (size_t)N * 256;          // [N,128] bf16
  ushort* x_l  = x_h + (size_t)N * 128;           // [N,128] bf16
  ushort* w1th = x_l + (size_t)N * 128;           // [256][128] x2
  ushort* w1tl = w1th + 256 * 128;
  ushort* w2th = w1tl + 256 * 128;                // [256][256] x2
  ushort* w2tl = w2th + 256 * 256;
  float*  zbuf = (float*)(w2tl + 256 * 256);      // a_s1,a_d1,a_s2,a_d2 [16N]
  float* a_s1 = zbuf;
  float* a_d1 = a_s1 + (size_t)N * 4;
  float* a_s2 = a_d1 + (size_t)N * 4;
  float* a_d2 = a_s2 + (size_t)N * 4;
  int* rowptr = (int*)(zbuf + (size_t)N * 16);    // [N+1] (+pad)
  int* cnt    = rowptr + (N + 4);                 // [N]
  int* cursor = cnt + N;                          // [N]
  int* colx   = cursor + N;                       // [E]
  int* partials = colx + E;                       // [<=256]

  const int nb = (N + 255) / 256;
  const int eb = (E + 255) / 256;

  hipMemsetAsync(cnt, 0, (size_t)N * 4, stream);
  k_hist<<<eb, 256, 0, stream>>>(dstv, cnt, E);
  k_scan_local<<<nb, 256, 0, stream>>>(cnt, rowptr, partials, N);
  k_scan_part<<<1, 256, 0, stream>>>(partials, nb);
  k_scan_add<<<nb, 256, 0, stream>>>(rowptr, partials, cursor, N, E);
  k_scatter<<<eb, 256, 0, stream>>>(srcv, dstv, cursor, colx, E);

  k_split_x<<<(N * 128 / 4 + 255) / 256, 256, 0, stream>>>(x, x_h, x_l, N * 128 / 4);
  k_prep_w<<<128, 256, 0, stream>>>(W1, w1th, w1tl, 128);
  k_prep_w<<<256, 256, 0, stream>>>(W2, w2th, w2tl, 256);

  dim3 gg(2, (N + 127) / 128);  // x = col half (adjacent -> A L2 reuse)
  const int wb = (N + 3) / 4;   // one wave per node

  k_gemm_mfma<<<gg, 256, 0, stream>>>(x_h, x_l, w1th, w1tl, h1, N, 128,
                                      as1, ad1, a_s1, a_d1);
  k_aggr<1><<<wb, 256, 0, stream>>>(h1, rowptr, colx, a_s1, a_d1, b1,
                                    hb_h, hb_l, nullptr, N);
  k_gemm_mfma<<<gg, 256, 0, stream>>>(hb_h, hb_l, w2th, w2tl, h1, N, 256,
                                      as2, ad2, a_s2, a_d2);
  k_aggr<2><<<wb, 256, 0, stream>>>(h1, rowptr, colx, a_s2, a_d2, b2,
                                    nullptr, nullptr, out, N);
}

// Round 11
// 420.486 us; speedup vs baseline: 1.5319x; 1.0132x over previous
//
#include <hip/hip_runtime.h>

// ---------------------------------------------------------------------------
// 2-layer GAT (PyG GATConv), MI355X.
// R11: XCD-aligned col-half pairing for k_gemm_mfma. R10 evidence: FETCH 93MB
//   = A fetched twice because adjacent blocks land on different XCDs
//   (round-robin %8); WRITE is eviction-dominated (LDS-transpose store was
//   neutral -> keep it, it's cheap). New 1-D grid swizzle: row-block r's two
//   col-halves get block ids differing by exactly 8 -> same XCD slot -> the
//   second A-tile read (131KB) hits that XCD's L2.
//   aggr / CSR / prep unchanged from R10.
// ---------------------------------------------------------------------------

typedef __attribute__((ext_vector_type(8))) short short8;
typedef __attribute__((ext_vector_type(4))) float f32x4;

static __device__ __forceinline__ ushort f2bf(float f) {  // RNE
  uint u = __float_as_uint(f);
  return (ushort)((u + 0x7FFFu + ((u >> 16) & 1u)) >> 16);
}
static __device__ __forceinline__ float bf2f(ushort s) {
  return __uint_as_float(((uint)s) << 16);
}

// ----------------------------- CSR build -----------------------------------
__global__ __launch_bounds__(256)
void k_hist(const int* __restrict__ dstv, int* __restrict__ cnt, int E) {
  int i = blockIdx.x * 256 + threadIdx.x;
  if (i < E) atomicAdd(&cnt[dstv[i]], 1);
}

__global__ __launch_bounds__(256)
void k_scan_local(const int* __restrict__ cnt, int* __restrict__ rowptr,
                  int* __restrict__ partials, int N) {
  __shared__ int sm[256];
  int gid = blockIdx.x * 256 + threadIdx.x;
  int v = (gid < N) ? cnt[gid] : 0;
  sm[threadIdx.x] = v;
  __syncthreads();
  for (int off = 1; off < 256; off <<= 1) {
    int t = (threadIdx.x >= (unsigned)off) ? sm[threadIdx.x - off] : 0;
    __syncthreads();
    sm[threadIdx.x] += t;
    __syncthreads();
  }
  if (gid < N) rowptr[gid] = sm[threadIdx.x] - v;  // exclusive
  if (threadIdx.x == 255) partials[blockIdx.x] = sm[255];
}

__global__ __launch_bounds__(256)
void k_scan_part(int* __restrict__ partials, int nb) {
  __shared__ int sm[256];
  int t = threadIdx.x;
  int v = (t < nb) ? partials[t] : 0;
  sm[t] = v;
  __syncthreads();
  for (int off = 1; off < 256; off <<= 1) {
    int u = (t >= off) ? sm[t - off] : 0;
    __syncthreads();
    sm[t] += u;
    __syncthreads();
  }
  if (t < nb) partials[t] = sm[t] - v;  // exclusive
}

__global__ __launch_bounds__(256)
void k_scan_add(int* __restrict__ rowptr, const int* __restrict__ partials,
                int* __restrict__ cursor, int N, int E) {
  int gid = blockIdx.x * 256 + threadIdx.x;
  if (gid < N) {
    int rp = rowptr[gid] + partials[blockIdx.x];
    rowptr[gid] = rp;
    cursor[gid] = rp;
  }
  if (gid == 0) rowptr[N] = E;
}

__global__ __launch_bounds__(256)
void k_scatter(const int* __restrict__ srcv, const int* __restrict__ dstv,
               int* __restrict__ cursor, int* __restrict__ col, int E) {
  int i = blockIdx.x * 256 + threadIdx.x;
  if (i < E) {
    int p = atomicAdd(&cursor[dstv[i]], 1);
    col[p] = srcv[i];
  }
}

// ----------------------------- prep: splits --------------------------------
__global__ __launch_bounds__(256)
void k_split_x(const float* __restrict__ x, ushort* __restrict__ xh,
               ushort* __restrict__ xl, int total4) {
  int gid = blockIdx.x * 256 + threadIdx.x;
  if (gid >= total4) return;
  float4 v = ((const float4*)x)[gid];
  ushort4 h, l;
  h.x = f2bf(v.x); l.x = f2bf(v.x - bf2f(h.x));
  h.y = f2bf(v.y); l.y = f2bf(v.y - bf2f(h.y));
  h.z = f2bf(v.z); l.z = f2bf(v.z - bf2f(h.z));
  h.w = f2bf(v.w); l.w = f2bf(v.w - bf2f(h.w));
  ((ushort4*)xh)[gid] = h;
  ((ushort4*)xl)[gid] = l;
}

__global__ __launch_bounds__(256)
void k_prep_w(const float* __restrict__ W, ushort* __restrict__ wth,
              ushort* __restrict__ wtl, int K) {
  int gid = blockIdx.x * 256 + threadIdx.x;  // gid < K*256
  int c = gid & 255, k = gid >> 8;
  float w = W[(size_t)k * 256 + c];
  ushort h = f2bf(w);
  wth[(size_t)c * K + k] = h;
  wtl[(size_t)c * K + k] = f2bf(w - bf2f(h));
}

// ----------------------------- MFMA GEMM -----------------------------------
// C[N,256] = (Ah+Al)[N,K] @ (Bh+Bl)[K,256], Bt stored [256][K].
// 1-D grid, XCD-aligned swizzle: bid = grp*16 + ch*8 + r8 where row block
// rb = grp*8 + r8, col half = ch. The two halves of rb differ by 8 block ids
// -> same XCD (round-robin %8) -> A tile's 2nd read hits local L2.
// Block 128x128, 4 waves 2x2, wave tile 64x64 = 4x4 MFMA 16x16x32 tiles,
// 3-term split-bf16. Epilogue: per-wave LDS transpose -> row-major short8
// stores; a_s/a_d from fp32 accs (plain stores).
__global__ __launch_bounds__(256)
void k_gemm_mfma(const ushort* __restrict__ Ah, const ushort* __restrict__ Al,
                 const ushort* __restrict__ Bth, const ushort* __restrict__ Btl,
                 ushort* __restrict__ hout, int Nrows, int K,
                 const float* __restrict__ att_s, const float* __restrict__ att_d,
                 float* __restrict__ a_s, float* __restrict__ a_d) {
  __shared__ ushort smem[4 * 128 * 40];  // As_h | As_l | Bs_h | Bs_l (K-loop)
                                         // reused post-loop: 4x 64x68 C tiles
  ushort* As_h = smem;
  ushort* As_l = smem + 128 * 40;
  ushort* Bs_h = smem + 2 * 128 * 40;
  ushort* Bs_l = smem + 3 * 128 * 40;

  // ---- XCD-aligned block swizzle
  const int nrb = (Nrows + 127) >> 7;
  const int bid = blockIdx.x;
  const int rb = (bid >> 4) * 8 + (bid & 7);
  const int ch = (bid >> 3) & 1;
  if (rb >= nrb) return;
  const int row0 = rb * 128;
  const int col0 = ch * 128;

  const int t = threadIdx.x;
  const int lane = t & 63;
  const int w = t >> 6;
  const int wr = (w >> 1) * 64;
  const int wc = (w & 1) * 64;
  const int lrow = t >> 2;       // 0..63 staging index
  const int kc = (t & 3) * 8;    // k-chunk within BK=32

  f32x4 acc[4][4] = {};

  uint4 pa_h[2], pa_l[2], pb_h[2], pb_l[2];
  const uint4 z4 = make_uint4(0, 0, 0, 0);
#pragma unroll
  for (int p = 0; p < 2; p++) {
    int gr = row0 + p * 64 + lrow;
    if (gr < Nrows) {
      pa_h[p] = *(const uint4*)(Ah + (size_t)gr * K + kc);
      pa_l[p] = *(const uint4*)(Al + (size_t)gr * K + kc);
    } else { pa_h[p] = z4; pa_l[p] = z4; }
    int gc = col0 + p * 64 + lrow;
    pb_h[p] = *(const uint4*)(Bth + (size_t)gc * K + kc);
    pb_l[p] = *(const uint4*)(Btl + (size_t)gc * K + kc);
  }

  const int fr = lane & 15;
  const int fq = lane >> 4;

  for (int k0 = 0; k0 < K; k0 += 32) {
#pragma unroll
    for (int p = 0; p < 2; p++) {
      *(uint4*)(&As_h[(p * 64 + lrow) * 40 + kc]) = pa_h[p];
      *(uint4*)(&As_l[(p * 64 + lrow) * 40 + kc]) = pa_l[p];
      *(uint4*)(&Bs_h[(p * 64 + lrow) * 40 + kc]) = pb_h[p];
      *(uint4*)(&Bs_l[(p * 64 + lrow) * 40 + kc]) = pb_l[p];
    }
    __syncthreads();

    if (k0 + 32 < K) {
#pragma unroll
      for (int p = 0; p < 2; p++) {
        int gr = row0 + p * 64 + lrow;
        if (gr < Nrows) {
          pa_h[p] = *(const uint4*)(Ah + (size_t)gr * K + k0 + 32 + kc);
          pa_l[p] = *(const uint4*)(Al + (size_t)gr * K + k0 + 32 + kc);
        } else { pa_h[p] = z4; pa_l[p] = z4; }
        int gc = col0 + p * 64 + lrow;
        pb_h[p] = *(const uint4*)(Bth + (size_t)gc * K + k0 + 32 + kc);
        pb_l[p] = *(const uint4*)(Btl + (size_t)gc * K + k0 + 32 + kc);
      }
    }

    short8 fa_h[4], fa_l[4], fb_h[4], fb_l[4];
#pragma unroll
    for (int r = 0; r < 4; r++) {
      fa_h[r] = *(const short8*)(&As_h[(wr + r * 16 + fr) * 40 + fq * 8]);
      fa_l[r] = *(const short8*)(&As_l[(wr + r * 16 + fr) * 40 + fq * 8]);
    }
#pragma unroll
    for (int c = 0; c < 4; c++) {
      fb_h[c] = *(const short8*)(&Bs_h[(wc + c * 16 + fr) * 40 + fq * 8]);
      fb_l[c] = *(const short8*)(&Bs_l[(wc + c * 16 + fr) * 40 + fq * 8]);
    }
#pragma unroll
    for (int r = 0; r < 4; r++)
#pragma unroll
      for (int c = 0; c < 4; c++) {
        acc[r][c] = __builtin_amdgcn_mfma_f32_16x16x32_bf16(fa_h[r], fb_h[c], acc[r][c], 0, 0, 0);
        acc[r][c] = __builtin_amdgcn_mfma_f32_16x16x32_bf16(fa_l[r], fb_h[c], acc[r][c], 0, 0, 0);
        acc[r][c] = __builtin_amdgcn_mfma_f32_16x16x32_bf16(fa_h[r], fb_l[c], acc[r][c], 0, 0, 0);
      }
    __syncthreads();
  }

  // ---- C write: wave-private LDS transpose -> coalesced row-major stores.
  {
    ushort* tile = smem + w * (64 * 68);  // 64 rows x 68 (pad) per wave
#pragma unroll
    for (int r = 0; r < 4; r++)
#pragma unroll
      for (int c = 0; c < 4; c++)
#pragma unroll
        for (int reg = 0; reg < 4; reg++)
          tile[(r * 16 + fq * 4 + reg) * 68 + c * 16 + fr] = f2bf(acc[r][c][reg]);
    const int rr = lane >> 3;        // 0..7
    const int cc = (lane & 7) * 8;   // 0..56
#pragma unroll
    for (int i = 0; i < 8; i++) {
      int row = i * 8 + rr;
      int gr = row0 + wr + row;
      if (gr < Nrows) {
        short8 v = *(const short8*)(&tile[row * 68 + cc]);
        *(short8*)(&hout[(size_t)gr * 256 + col0 + wc + cc]) = v;
      }
    }
  }

  // ---- attention scores: wave's 64 cols = one head (wc 64-aligned)
  const int head = (col0 + wc) >> 6;
  float asv[4], adv[4];
#pragma unroll
  for (int c = 0; c < 4; c++) {
    asv[c] = att_s[col0 + wc + c * 16 + fr];
    adv[c] = att_d[col0 + wc + c * 16 + fr];
  }
#pragma unroll
  for (int r = 0; r < 4; r++)
#pragma unroll
    for (int reg = 0; reg < 4; reg++) {
      float ps = 0.f, pd = 0.f;
#pragma unroll
      for (int c = 0; c < 4; c++) {
        ps += acc[r][c][reg] * asv[c];
        pd += acc[r][c][reg] * adv[c];
      }
      ps += __shfl_xor(ps, 1); pd += __shfl_xor(pd, 1);
      ps += __shfl_xor(ps, 2); pd += __shfl_xor(pd, 2);
      ps += __shfl_xor(ps, 4); pd += __shfl_xor(pd, 4);
      ps += __shfl_xor(ps, 8); pd += __shfl_xor(pd, 8);
      if (fr == 0) {
        int gr = row0 + wr + r * 16 + fq * 4 + reg;
        if (gr < Nrows) {
          a_s[(size_t)gr * 4 + head] = ps;
          a_d[(size_t)gr * 4 + head] = pd;
        }
      }
    }
}

// ----------------------------- aggregation ---------------------------------
// ONE wave per node; lane owns channels [4*lane, 4*lane+3] (ushort4 gather),
// head = lane>>4. Chunk of 64 edges: lane gathers a_s[col] float4, computes
// all-head weights inline, stages (src, w[4]) in LDS. Denominator free.
// LAYER 1: relu(acc/den + bias) -> split bf16 (out_h, out_l).
// LAYER 2: fused finale — head-mean + bias + relu + softmax(64) -> outp.
template <int LAYER>
__global__ __launch_bounds__(256)
void k_aggr(const ushort* __restrict__ hsrc, const int* __restrict__ rowptr,
            const int* __restrict__ col, const float* __restrict__ a_s,
            const float* __restrict__ a_d, const float* __restrict__ bias,
            ushort* __restrict__ out_h, ushort* __restrict__ out_l,
            float* __restrict__ outp, int N) {
  __shared__ int   s_sh[4][64];
  __shared__ float w_sh[4][256];
  const int wv = threadIdx.x >> 6;
  const int lane = threadIdx.x & 63;
  const int node = blockIdx.x * 4 + wv;
  if (node >= N) return;
  const int hd = lane >> 4;
  const int beg = rowptr[node], end = rowptr[node + 1];
  const float4 adst = *(const float4*)(a_d + (size_t)node * 4);

  float4 acc = make_float4(0.f, 0.f, 0.f, 0.f);
  float wsum = 0.f;
  const char* hbase = (const char*)(hsrc + lane * 4);

  for (int c0 = beg; c0 < end; c0 += 64) {
    int nc = min(64, end - c0);
    int s = 0;
    float4 w4 = make_float4(0.f, 0.f, 0.f, 0.f);
    if (lane < nc) {
      s = col[c0 + lane];
      float4 a = *(const float4*)(a_s + (size_t)s * 4);
      float e0 = a.x + adst.x; e0 = e0 > 0.f ? e0 : 0.2f * e0;
      float e1 = a.y + adst.y; e1 = e1 > 0.f ? e1 : 0.2f * e1;
      float e2 = a.z + adst.z; e2 = e2 > 0.f ? e2 : 0.2f * e2;
      float e3 = a.w + adst.w; e3 = e3 > 0.f ? e3 : 0.2f * e3;
      w4 = make_float4(__expf(e0), __expf(e1), __expf(e2), __expf(e3));
    }
    s_sh[wv][lane] = s;
    *(float4*)(&w_sh[wv][lane * 4]) = w4;
    asm volatile("s_waitcnt lgkmcnt(0)" ::: "memory");

    const float* wrow = &w_sh[wv][hd];
    const int*   srow = &s_sh[wv][0];
    int j = 0;
    for (; j + 4 <= nc; j += 4) {
      int sj0 = srow[j], sj1 = srow[j + 1], sj2 = srow[j + 2], sj3 = srow[j + 3];
      float w0 = wrow[4 * j],      w1 = wrow[4 * j + 4];
      float w2 = wrow[4 * j + 8],  w3 = wrow[4 * j + 12];
      ushort4 u0 = *(const ushort4*)(hbase + ((size_t)((uint)sj0 << 9)));
      ushort4 u1 = *(const ushort4*)(hbase + ((size_t)((uint)sj1 << 9)));
      ushort4 u2 = *(const ushort4*)(hbase + ((size_t)((uint)sj2 << 9)));
      ushort4 u3 = *(const ushort4*)(hbase + ((size_t)((uint)sj3 << 9)));
      wsum += w0 + w1 + w2 + w3;
      acc.x += w0 * bf2f(u0.x); acc.y += w0 * bf2f(u0.y);
      acc.z += w0 * bf2f(u0.z); acc.w += w0 * bf2f(u0.w);
      acc.x += w1 * bf2f(u1.x); acc.y += w1 * bf2f(u1.y);
      acc.z += w1 * bf2f(u1.z); acc.w += w1 * bf2f(u1.w);
      acc.x += w2 * bf2f(u2.x); acc.y += w2 * bf2f(u2.y);
      acc.z += w2 * bf2f(u2.z); acc.w += w2 * bf2f(u2.w);
      acc.x += w3 * bf2f(u3.x); acc.y += w3 * bf2f(u3.y);
      acc.z += w3 * bf2f(u3.z); acc.w += w3 * bf2f(u3.w);
    }
    for (; j < nc; j++) {
      int sj = srow[j];
      float ww = wrow[4 * j];
      ushort4 u = *(const ushort4*)(hbase + ((size_t)((uint)sj << 9)));
      wsum += ww;
      acc.x += ww * bf2f(u.x); acc.y += ww * bf2f(u.y);
      acc.z += ww * bf2f(u.z); acc.w += ww * bf2f(u.w);
    }
  }

  float inv = 1.0f / wsum;  // deg>=1 via self-loop
  float4 v = make_float4(acc.x * inv, acc.y * inv, acc.z * inv, acc.w * inv);

  if (LAYER == 1) {
    const float4 bv = *(const float4*)(bias + lane * 4);
    v.x = fmaxf(v.x + bv.x, 0.f);
    v.y = fmaxf(v.y + bv.y, 0.f);
    v.z = fmaxf(v.z + bv.z, 0.f);
    v.w = fmaxf(v.w + bv.w, 0.f);
    ushort4 h, l;
    h.x = f2bf(v.x); l.x = f2bf(v.x - bf2f(h.x));
    h.y = f2bf(v.y); l.y = f2bf(v.y - bf2f(h.y));
    h.z = f2bf(v.z); l.z = f2bf(v.z - bf2f(h.z));
    h.w = f2bf(v.w); l.w = f2bf(v.w - bf2f(h.w));
    const size_t o = (size_t)node * 256 + lane * 4;
    *(ushort4*)(out_h + o) = h;
    *(ushort4*)(out_l + o) = l;
  } else {
    // fused finale: head-mean + bias + relu + softmax(64)
    v.x += __shfl_xor(v.x, 16); v.y += __shfl_xor(v.y, 16);
    v.z += __shfl_xor(v.z, 16); v.w += __shfl_xor(v.w, 16);
    v.x += __shfl_xor(v.x, 32); v.y += __shfl_xor(v.y, 32);
    v.z += __shfl_xor(v.z, 32); v.w += __shfl_xor(v.w, 32);
    const int c4 = (lane & 15) * 4;
    const float4 bv = *(const float4*)(bias + c4);
    v.x = fmaxf(v.x * 0.25f + bv.x, 0.f);
    v.y = fmaxf(v.y * 0.25f + bv.y, 0.f);
    v.z = fmaxf(v.z * 0.25f + bv.z, 0.f);
    v.w = fmaxf(v.w * 0.25f + bv.w, 0.f);
    float mx = fmaxf(fmaxf(v.x, v.y), fmaxf(v.z, v.w));
    for (int off = 8; off >= 1; off >>= 1) mx = fmaxf(mx, __shfl_xor(mx, off));
    v.x = __expf(v.x - mx); v.y = __expf(v.y - mx);
    v.z = __expf(v.z - mx); v.w = __expf(v.w - mx);
    float sum = v.x + v.y + v.z + v.w;
    for (int off = 8; off >= 1; off >>= 1) sum += __shfl_xor(sum, off);
    float is = 1.0f / sum;
    v.x *= is; v.y *= is; v.z *= is; v.w *= is;
    if (lane < 16) *(float4*)(outp + (size_t)node * 64 + c4) = v;
  }
}

// ---------------------------------------------------------------------------

extern "C" void kernel_launch(void* const* d_in, const int* in_sizes, int n_in,
                              void* d_out, int out_size, void* d_ws, size_t ws_size,
                              hipStream_t stream) {
  const float* x   = (const float*)d_in[0];
  const int*   ei  = (const int*)d_in[1];
  const float* W1  = (const float*)d_in[2];
  const float* as1 = (const float*)d_in[3];
  const float* ad1 = (const float*)d_in[4];
  const float* b1  = (const float*)d_in[5];
  const float* W2  = (const float*)d_in[6];
  const float* as2 = (const float*)d_in[7];
  const float* ad2 = (const float*)d_in[8];
  const float* b2  = (const float*)d_in[9];
  float* out = (float*)d_out;

  const int N = in_sizes[0] / 128;
  const int E = in_sizes[1] / 2;
  const int* srcv = ei;
  const int* dstv = ei + E;

  // ---- workspace layout
  ushort* h1   = (ushort*)d_ws;                   // [N,256] bf16 (also h2)
  ushort* hb_h = h1 + (size_t)N * 256;            // [N,256] bf16
  ushort* hb_l = hb_h + (size_t)N * 256;          // [N,256] bf16
  ushort* x_h  = hb_l + (size_t)N * 256;          // [N,128] bf16
  ushort* x_l  = x_h + (size_t)N * 128;           // [N,128] bf16
  ushort* w1th = x_l + (size_t)N * 128;           // [256][128] x2
  ushort* w1tl = w1th + 256 * 128;
  ushort* w2th = w1tl + 256 * 128;                // [256][256] x2
  ushort* w2tl = w2th + 256 * 256;
  float*  zbuf = (float*)(w2tl + 256 * 256);      // a_s1,a_d1,a_s2,a_d2 [16N]
  float* a_s1 = zbuf;
  float* a_d1 = a_s1 + (size_t)N * 4;
  float* a_s2 = a_d1 + (size_t)N * 4;
  float* a_d2 = a_s2 + (size_t)N * 4;
  int* rowptr = (int*)(zbuf + (size_t)N * 16);    // [N+1] (+pad)
  int* cnt    = rowptr + (N + 4);                 // [N]
  int* cursor = cnt + N;                          // [N]
  int* colx   = cursor + N;                       // [E]
  int* partials = colx + E;                       // [<=256]

  const int nb = (N + 255) / 256;
  const int eb = (E + 255) / 256;

  hipMemsetAsync(cnt, 0, (size_t)N * 4, stream);
  k_hist<<<eb, 256, 0, stream>>>(dstv, cnt, E);
  k_scan_local<<<nb, 256, 0, stream>>>(cnt, rowptr, partials, N);
  k_scan_part<<<1, 256, 0, stream>>>(partials, nb);
  k_scan_add<<<nb, 256, 0, stream>>>(rowptr, partials, cursor, N, E);
  k_scatter<<<eb, 256, 0, stream>>>(srcv, dstv, cursor, colx, E);

  k_split_x<<<(N * 128 / 4 + 255) / 256, 256, 0, stream>>>(x, x_h, x_l, N * 128 / 4);
  k_prep_w<<<128, 256, 0, stream>>>(W1, w1th, w1tl, 128);
  k_prep_w<<<256, 256, 0, stream>>>(W2, w2th, w2tl, 256);

  // XCD-aligned swizzled 1-D grid: 16 blocks per group of 8 row blocks
  const int nrb = (N + 127) / 128;
  const int gemm_blocks = ((nrb + 7) / 8) * 16;
  const int wb = (N + 3) / 4;  // one wave per node

  k_gemm_mfma<<<gemm_blocks, 256, 0, stream>>>(x_h, x_l, w1th, w1tl, h1, N, 128,
                                               as1, ad1, a_s1, a_d1);
  k_aggr<1><<<wb, 256, 0, stream>>>(h1, rowptr, colx, a_s1, a_d1, b1,
                                    hb_h, hb_l, nullptr, N);
  k_gemm_mfma<<<gemm_blocks, 256, 0, stream>>>(hb_h, hb_l, w2th, w2tl, h1, N, 256,
                                               as2, ad2, a_s2, a_d2);
  k_aggr<2><<<wb, 256, 0, stream>>>(h1, rowptr, colx, a_s2, a_d2, b2,
                                    nullptr, nullptr, out, N);
}

// Round 12
// 405.821 us; speedup vs baseline: 1.5872x; 1.0361x over previous
//
#include <hip/hip_runtime.h>

// ---------------------------------------------------------------------------
// 2-layer GAT (PyG GATConv), MI355X.
// R12: (1) gemm: B fragments loaded straight from global (L1/L2-resident
//      256KB panel) — kills B LDS staging (R11 gemm was LDS-pipe-bound ~5x:
//      24 ds-ops/230 MFMA cyc, MfmaUtil 10%). LDS now A-only 20.5KB. C-write
//      back to direct bf16 stores (R10 proved LDS-transpose neutral).
//      (2) gemm1 splits fp32 x inline during staging -> k_split_x deleted.
//      (3) scan_local/part/add -> ONE lookback scan (196 blocks co-resident
//      on 256 CUs -> spin safe); prep_w1+prep_w2 -> one dispatch.
//      13 -> 9 dispatches. aggr unchanged from R11.
// ---------------------------------------------------------------------------

typedef __attribute__((ext_vector_type(8))) short short8;
typedef __attribute__((ext_vector_type(4))) float f32x4;

static __device__ __forceinline__ ushort f2bf(float f) {  // RNE
  uint u = __float_as_uint(f);
  return (ushort)((u + 0x7FFFu + ((u >> 16) & 1u)) >> 16);
}
static __device__ __forceinline__ float bf2f(ushort s) {
  return __uint_as_float(((uint)s) << 16);
}
static __device__ __forceinline__ void split8(const float4& a, const float4& b,
                                              uint4& hh, uint4& ll) {
  ushort h0 = f2bf(a.x), h1 = f2bf(a.y), h2 = f2bf(a.z), h3 = f2bf(a.w);
  ushort h4 = f2bf(b.x), h5 = f2bf(b.y), h6 = f2bf(b.z), h7 = f2bf(b.w);
  hh.x = (uint)h0 | ((uint)h1 << 16); hh.y = (uint)h2 | ((uint)h3 << 16);
  hh.z = (uint)h4 | ((uint)h5 << 16); hh.w = (uint)h6 | ((uint)h7 << 16);
  ll.x = (uint)f2bf(a.x - bf2f(h0)) | ((uint)f2bf(a.y - bf2f(h1)) << 16);
  ll.y = (uint)f2bf(a.z - bf2f(h2)) | ((uint)f2bf(a.w - bf2f(h3)) << 16);
  ll.z = (uint)f2bf(b.x - bf2f(h4)) | ((uint)f2bf(b.y - bf2f(h5)) << 16);
  ll.w = (uint)f2bf(b.z - bf2f(h6)) | ((uint)f2bf(b.w - bf2f(h7)) << 16);
}

// ----------------------------- CSR build -----------------------------------
__global__ __launch_bounds__(256)
void k_hist(const int* __restrict__ dstv, int* __restrict__ cnt, int E) {
  int i = blockIdx.x * 256 + threadIdx.x;
  if (i < E) atomicAdd(&cnt[dstv[i]], 1);
}

// Single-pass exclusive scan with decoupled lookback. Grid <= 256 blocks
// (all co-resident on 256 CUs -> spinning is deadlock-free). bflag zeroed by
// the host-side memset each launch.
__global__ __launch_bounds__(256)
void k_scan(const int* __restrict__ cnt, int* __restrict__ rowptr,
            int* __restrict__ cursor, int* __restrict__ bsum,
            int* __restrict__ bflag, int N, int E) {
  __shared__ int sm[256];
  __shared__ int s_prev;
  const int b = blockIdx.x, tid = threadIdx.x;
  const int gid = b * 256 + tid;
  int v = (gid < N) ? cnt[gid] : 0;
  sm[tid] = v;
  __syncthreads();
  for (int off = 1; off < 256; off <<= 1) {
    int t = (tid >= off) ? sm[tid - off] : 0;
    __syncthreads();
    sm[tid] += t;
    __syncthreads();
  }
  if (tid == 255) {
    atomicExch(&bsum[b], sm[255]);
    __threadfence();
    atomicExch(&bflag[b], 1);
  }
  if (tid == 0) s_prev = 0;
  __syncthreads();
  if (tid < b) {  // gridDim<=256 -> each thread polls at most one block
    while (atomicAdd(&bflag[tid], 0) == 0) {}
    atomicAdd(&s_prev, atomicAdd(&bsum[tid], 0));
  }
  __syncthreads();
  if (gid < N) {
    int rp = s_prev + sm[tid] - v;
    rowptr[gid] = rp;
    cursor[gid] = rp;
  }
  if (gid == 0) rowptr[N] = E;
}

__global__ __launch_bounds__(256)
void k_scatter(const int* __restrict__ srcv, const int* __restrict__ dstv,
               int* __restrict__ cursor, int* __restrict__ col, int E) {
  int i = blockIdx.x * 256 + threadIdx.x;
  if (i < E) {
    int p = atomicAdd(&cursor[dstv[i]], 1);
    col[p] = srcv[i];
  }
}

// --------------------- weight prep (both layers, one launch) ---------------
__global__ __launch_bounds__(256)
void k_prep_w(const float* __restrict__ W1, const float* __restrict__ W2,
              ushort* __restrict__ w1th, ushort* __restrict__ w1tl,
              ushort* __restrict__ w2th, ushort* __restrict__ w2tl) {
  int bid = blockIdx.x;
  if (bid < 128) {  // W1 [128][256] -> [256][128] split
    int gid = bid * 256 + threadIdx.x;
    int c = gid & 255, k = gid >> 8;
    float w = W1[(size_t)k * 256 + c];
    ushort h = f2bf(w);
    w1th[(size_t)c * 128 + k] = h;
    w1tl[(size_t)c * 128 + k] = f2bf(w - bf2f(h));
  } else {          // W2 [256][256] -> [256][256] split
    int gid = (bid - 128) * 256 + threadIdx.x;
    int c = gid & 255, k = gid >> 8;
    float w = W2[(size_t)k * 256 + c];
    ushort h = f2bf(w);
    w2th[(size_t)c * 256 + k] = h;
    w2tl[(size_t)c * 256 + k] = f2bf(w - bf2f(h));
  }
}

// ----------------------------- MFMA GEMM -----------------------------------
// C[N,256] = (Ah+Al)[N,K] @ (Bh+Bl)[K,256], Bt stored [256][K].
// SPLIT=1: A is fp32 (x), split to bf16 h/l inline during LDS staging.
// SPLIT=0: A given as pre-split bf16 (hb_h, hb_l).
// B fragments loaded per k-tile directly from global (panel is L1/L2-hot;
// each short8 load covers 16 cache lines exactly). LDS holds A only.
// XCD-aligned 1-D swizzle (R11): the two col-halves of a row block differ by
// 8 block ids -> same XCD -> A's 2nd read hits local L2.
template <int SPLIT>
__global__ __launch_bounds__(256)
void k_gemm_mfma(const void* __restrict__ Aany, const ushort* __restrict__ Al_,
                 const ushort* __restrict__ Bth, const ushort* __restrict__ Btl,
                 ushort* __restrict__ hout, int Nrows, int K,
                 const float* __restrict__ att_s, const float* __restrict__ att_d,
                 float* __restrict__ a_s, float* __restrict__ a_d) {
  __shared__ ushort As_h[128][40];
  __shared__ ushort As_l[128][40];

  const int nrb = (Nrows + 127) >> 7;
  const int bid = blockIdx.x;
  const int rb = (bid >> 4) * 8 + (bid & 7);
  const int ch = (bid >> 3) & 1;
  if (rb >= nrb) return;
  const int row0 = rb * 128;
  const int col0 = ch * 128;

  const int t = threadIdx.x;
  const int lane = t & 63;
  const int w = t >> 6;
  const int wr = (w >> 1) * 64;
  const int wc = (w & 1) * 64;
  const int lrow = t >> 2;       // 0..63 staging row index
  const int kc = (t & 3) * 8;    // k-chunk within BK=32

  const float*  Af = (const float*)Aany;    // SPLIT=1
  const ushort* Ah = (const ushort*)Aany;   // SPLIT=0

  f32x4 acc[4][4] = {};

  // prefetch tile 0
  float4 pf[2][2];
  uint4 pa_h[2], pa_l[2];
  const uint4 z4 = make_uint4(0, 0, 0, 0);
#pragma unroll
  for (int p = 0; p < 2; p++) {
    int gr = row0 + p * 64 + lrow;
    if (SPLIT) {
      if (gr < Nrows) {
        const float* ap = Af + (size_t)gr * K + kc;
        pf[p][0] = *(const float4*)(ap);
        pf[p][1] = *(const float4*)(ap + 4);
      } else {
        pf[p][0] = make_float4(0.f, 0.f, 0.f, 0.f);
        pf[p][1] = pf[p][0];
      }
    } else {
      if (gr < Nrows) {
        pa_h[p] = *(const uint4*)(Ah + (size_t)gr * K + kc);
        pa_l[p] = *(const uint4*)(Al_ + (size_t)gr * K + kc);
      } else { pa_h[p] = z4; pa_l[p] = z4; }
    }
  }

  const int fr = lane & 15;
  const int fq = lane >> 4;
  // B fragment base: column col0+wc+c*16+fr, k offset fq*8
  const ushort* bb_h = Bth + (size_t)(col0 + wc + fr) * K + fq * 8;
  const ushort* bb_l = Btl + (size_t)(col0 + wc + fr) * K + fq * 8;

  for (int k0 = 0; k0 < K; k0 += 32) {
    // commit prefetched A tile to LDS
#pragma unroll
    for (int p = 0; p < 2; p++) {
      uint4 hh, ll;
      if (SPLIT) split8(pf[p][0], pf[p][1], hh, ll);
      else { hh = pa_h[p]; ll = pa_l[p]; }
      *(uint4*)(&As_h[p * 64 + lrow][kc]) = hh;
      *(uint4*)(&As_l[p * 64 + lrow][kc]) = ll;
    }
    __syncthreads();

    // prefetch next A tile (global, hidden under compute)
    if (k0 + 32 < K) {
#pragma unroll
      for (int p = 0; p < 2; p++) {
        int gr = row0 + p * 64 + lrow;
        if (SPLIT) {
          if (gr < Nrows) {
            const float* ap = Af + (size_t)gr * K + k0 + 32 + kc;
            pf[p][0] = *(const float4*)(ap);
            pf[p][1] = *(const float4*)(ap + 4);
          } else {
            pf[p][0] = make_float4(0.f, 0.f, 0.f, 0.f);
            pf[p][1] = pf[p][0];
          }
        } else {
          if (gr < Nrows) {
            pa_h[p] = *(const uint4*)(Ah + (size_t)gr * K + k0 + 32 + kc);
            pa_l[p] = *(const uint4*)(Al_ + (size_t)gr * K + k0 + 32 + kc);
          } else { pa_h[p] = z4; pa_l[p] = z4; }
        }
      }
    }

    // B fragments direct from global (L1/L2-hot panel)
    short8 fb_h[4], fb_l[4];
#pragma unroll
    for (int c = 0; c < 4; c++) {
      fb_h[c] = *(const short8*)(bb_h + (size_t)c * 16 * K + k0);
      fb_l[c] = *(const short8*)(bb_l + (size_t)c * 16 * K + k0);
    }
    // A fragments from LDS
    short8 fa_h[4], fa_l[4];
#pragma unroll
    for (int r = 0; r < 4; r++) {
      fa_h[r] = *(const short8*)(&As_h[wr + r * 16 + fr][fq * 8]);
      fa_l[r] = *(const short8*)(&As_l[wr + r * 16 + fr][fq * 8]);
    }
#pragma unroll
    for (int r = 0; r < 4; r++)
#pragma unroll
      for (int c = 0; c < 4; c++) {
        acc[r][c] = __builtin_amdgcn_mfma_f32_16x16x32_bf16(fa_h[r], fb_h[c], acc[r][c], 0, 0, 0);
        acc[r][c] = __builtin_amdgcn_mfma_f32_16x16x32_bf16(fa_l[r], fb_h[c], acc[r][c], 0, 0, 0);
        acc[r][c] = __builtin_amdgcn_mfma_f32_16x16x32_bf16(fa_h[r], fb_l[c], acc[r][c], 0, 0, 0);
      }
    __syncthreads();
  }

  // ---- C write (bf16, direct — R10 showed L2 absorbs the 2B scatter)
#pragma unroll
  for (int r = 0; r < 4; r++)
#pragma unroll
    for (int c = 0; c < 4; c++) {
      int colg = col0 + wc + c * 16 + fr;
#pragma unroll
      for (int reg = 0; reg < 4; reg++) {
        int gr = row0 + wr + r * 16 + fq * 4 + reg;
        if (gr < Nrows) hout[(size_t)gr * 256 + colg] = f2bf(acc[r][c][reg]);
      }
    }

  // ---- attention scores: wave's 64 cols = one head (wc 64-aligned)
  const int head = (col0 + wc) >> 6;
  float asv[4], adv[4];
#pragma unroll
  for (int c = 0; c < 4; c++) {
    asv[c] = att_s[col0 + wc + c * 16 + fr];
    adv[c] = att_d[col0 + wc + c * 16 + fr];
  }
#pragma unroll
  for (int r = 0; r < 4; r++)
#pragma unroll
    for (int reg = 0; reg < 4; reg++) {
      float ps = 0.f, pd = 0.f;
#pragma unroll
      for (int c = 0; c < 4; c++) {
        ps += acc[r][c][reg] * asv[c];
        pd += acc[r][c][reg] * adv[c];
      }
      ps += __shfl_xor(ps, 1); pd += __shfl_xor(pd, 1);
      ps += __shfl_xor(ps, 2); pd += __shfl_xor(pd, 2);
      ps += __shfl_xor(ps, 4); pd += __shfl_xor(pd, 4);
      ps += __shfl_xor(ps, 8); pd += __shfl_xor(pd, 8);
      if (fr == 0) {
        int gr = row0 + wr + r * 16 + fq * 4 + reg;
        if (gr < Nrows) {
          a_s[(size_t)gr * 4 + head] = ps;
          a_d[(size_t)gr * 4 + head] = pd;
        }
      }
    }
}

// ----------------------------- aggregation ---------------------------------
// ONE wave per node; lane owns channels [4*lane, 4*lane+3] (ushort4 gather),
// head = lane>>4. Chunk of 64 edges: lane gathers a_s[col] float4, computes
// all-head weights inline, stages (src, w[4]) in LDS. Denominator free.
// LAYER 1: relu(acc/den + bias) -> split bf16 (out_h, out_l).
// LAYER 2: fused finale — head-mean + bias + relu + softmax(64) -> outp.
template <int LAYER>
__global__ __launch_bounds__(256)
void k_aggr(const ushort* __restrict__ hsrc, const int* __restrict__ rowptr,
            const int* __restrict__ col, const float* __restrict__ a_s,
            const float* __restrict__ a_d, const float* __restrict__ bias,
            ushort* __restrict__ out_h, ushort* __restrict__ out_l,
            float* __restrict__ outp, int N) {
  __shared__ int   s_sh[4][64];
  __shared__ float w_sh[4][256];
  const int wv = threadIdx.x >> 6;
  const int lane = threadIdx.x & 63;
  const int node = blockIdx.x * 4 + wv;
  if (node >= N) return;
  const int hd = lane >> 4;
  const int beg = rowptr[node], end = rowptr[node + 1];
  const float4 adst = *(const float4*)(a_d + (size_t)node * 4);

  float4 acc = make_float4(0.f, 0.f, 0.f, 0.f);
  float wsum = 0.f;
  const char* hbase = (const char*)(hsrc + lane * 4);

  for (int c0 = beg; c0 < end; c0 += 64) {
    int nc = min(64, end - c0);
    int s = 0;
    float4 w4 = make_float4(0.f, 0.f, 0.f, 0.f);
    if (lane < nc) {
      s = col[c0 + lane];
      float4 a = *(const float4*)(a_s + (size_t)s * 4);
      float e0 = a.x + adst.x; e0 = e0 > 0.f ? e0 : 0.2f * e0;
      float e1 = a.y + adst.y; e1 = e1 > 0.f ? e1 : 0.2f * e1;
      float e2 = a.z + adst.z; e2 = e2 > 0.f ? e2 : 0.2f * e2;
      float e3 = a.w + adst.w; e3 = e3 > 0.f ? e3 : 0.2f * e3;
      w4 = make_float4(__expf(e0), __expf(e1), __expf(e2), __expf(e3));
    }
    s_sh[wv][lane] = s;
    *(float4*)(&w_sh[wv][lane * 4]) = w4;
    asm volatile("s_waitcnt lgkmcnt(0)" ::: "memory");

    const float* wrow = &w_sh[wv][hd];
    const int*   srow = &s_sh[wv][0];
    int j = 0;
    for (; j + 4 <= nc; j += 4) {
      int sj0 = srow[j], sj1 = srow[j + 1], sj2 = srow[j + 2], sj3 = srow[j + 3];
      float w0 = wrow[4 * j],      w1 = wrow[4 * j + 4];
      float w2 = wrow[4 * j + 8],  w3 = wrow[4 * j + 12];
      ushort4 u0 = *(const ushort4*)(hbase + ((size_t)((uint)sj0 << 9)));
      ushort4 u1 = *(const ushort4*)(hbase + ((size_t)((uint)sj1 << 9)));
      ushort4 u2 = *(const ushort4*)(hbase + ((size_t)((uint)sj2 << 9)));
      ushort4 u3 = *(const ushort4*)(hbase + ((size_t)((uint)sj3 << 9)));
      wsum += w0 + w1 + w2 + w3;
      acc.x += w0 * bf2f(u0.x); acc.y += w0 * bf2f(u0.y);
      acc.z += w0 * bf2f(u0.z); acc.w += w0 * bf2f(u0.w);
      acc.x += w1 * bf2f(u1.x); acc.y += w1 * bf2f(u1.y);
      acc.z += w1 * bf2f(u1.z); acc.w += w1 * bf2f(u1.w);
      acc.x += w2 * bf2f(u2.x); acc.y += w2 * bf2f(u2.y);
      acc.z += w2 * bf2f(u2.z); acc.w += w2 * bf2f(u2.w);
      acc.x += w3 * bf2f(u3.x); acc.y += w3 * bf2f(u3.y);
      acc.z += w3 * bf2f(u3.z); acc.w += w3 * bf2f(u3.w);
    }
    for (; j < nc; j++) {
      int sj = srow[j];
      float ww = wrow[4 * j];
      ushort4 u = *(const ushort4*)(hbase + ((size_t)((uint)sj << 9)));
      wsum += ww;
      acc.x += ww * bf2f(u.x); acc.y += ww * bf2f(u.y);
      acc.z += ww * bf2f(u.z); acc.w += ww * bf2f(u.w);
    }
  }

  float inv = 1.0f / wsum;  // deg>=1 via self-loop
  float4 v = make_float4(acc.x * inv, acc.y * inv, acc.z * inv, acc.w * inv);

  if (LAYER == 1) {
    const float4 bv = *(const float4*)(bias + lane * 4);
    v.x = fmaxf(v.x + bv.x, 0.f);
    v.y = fmaxf(v.y + bv.y, 0.f);
    v.z = fmaxf(v.z + bv.z, 0.f);
    v.w = fmaxf(v.w + bv.w, 0.f);
    ushort4 h, l;
    h.x = f2bf(v.x); l.x = f2bf(v.x - bf2f(h.x));
    h.y = f2bf(v.y); l.y = f2bf(v.y - bf2f(h.y));
    h.z = f2bf(v.z); l.z = f2bf(v.z - bf2f(h.z));
    h.w = f2bf(v.w); l.w = f2bf(v.w - bf2f(h.w));
    const size_t o = (size_t)node * 256 + lane * 4;
    *(ushort4*)(out_h + o) = h;
    *(ushort4*)(out_l + o) = l;
  } else {
    // fused finale: head-mean + bias + relu + softmax(64)
    v.x += __shfl_xor(v.x, 16); v.y += __shfl_xor(v.y, 16);
    v.z += __shfl_xor(v.z, 16); v.w += __shfl_xor(v.w, 16);
    v.x += __shfl_xor(v.x, 32); v.y += __shfl_xor(v.y, 32);
    v.z += __shfl_xor(v.z, 32); v.w += __shfl_xor(v.w, 32);
    const int c4 = (lane & 15) * 4;
    const float4 bv = *(const float4*)(bias + c4);
    v.x = fmaxf(v.x * 0.25f + bv.x, 0.f);
    v.y = fmaxf(v.y * 0.25f + bv.y, 0.f);
    v.z = fmaxf(v.z * 0.25f + bv.z, 0.f);
    v.w = fmaxf(v.w * 0.25f + bv.w, 0.f);
    float mx = fmaxf(fmaxf(v.x, v.y), fmaxf(v.z, v.w));
    for (int off = 8; off >= 1; off >>= 1) mx = fmaxf(mx, __shfl_xor(mx, off));
    v.x = __expf(v.x - mx); v.y = __expf(v.y - mx);
    v.z = __expf(v.z - mx); v.w = __expf(v.w - mx);
    float sum = v.x + v.y + v.z + v.w;
    for (int off = 8; off >= 1; off >>= 1) sum += __shfl_xor(sum, off);
    float is = 1.0f / sum;
    v.x *= is; v.y *= is; v.z *= is; v.w *= is;
    if (lane < 16) *(float4*)(outp + (size_t)node * 64 + c4) = v;
  }
}

// ---------------------------------------------------------------------------

extern "C" void kernel_launch(void* const* d_in, const int* in_sizes, int n_in,
                              void* d_out, int out_size, void* d_ws, size_t ws_size,
                              hipStream_t stream) {
  const float* x   = (const float*)d_in[0];
  const int*   ei  = (const int*)d_in[1];
  const float* W1  = (const float*)d_in[2];
  const float* as1 = (const float*)d_in[3];
  const float* ad1 = (const float*)d_in[4];
  const float* b1  = (const float*)d_in[5];
  const float* W2  = (const float*)d_in[6];
  const float* as2 = (const float*)d_in[7];
  const float* ad2 = (const float*)d_in[8];
  const float* b2  = (const float*)d_in[9];
  float* out = (float*)d_out;

  const int N = in_sizes[0] / 128;
  const int E = in_sizes[1] / 2;
  const int* srcv = ei;
  const int* dstv = ei + E;

  // ---- workspace layout
  ushort* h1   = (ushort*)d_ws;                   // [N,256] bf16 (also h2)
  ushort* hb_h = h1 + (size_t)N * 256;            // [N,256] bf16
  ushort* hb_l = hb_h + (size_t)N * 256;          // [N,256] bf16
  ushort* w1th = hb_l + (size_t)N * 256;          // [256][128] x2
  ushort* w1tl = w1th + 256 * 128;
  ushort* w2th = w1tl + 256 * 128;                // [256][256] x2
  ushort* w2tl = w2th + 256 * 256;
  float*  zbuf = (float*)(w2tl + 256 * 256);      // a_s1,a_d1,a_s2,a_d2 [16N]
  float* a_s1 = zbuf;
  float* a_d1 = a_s1 + (size_t)N * 4;
  float* a_s2 = a_d1 + (size_t)N * 4;
  float* a_d2 = a_s2 + (size_t)N * 4;
  int* rowptr = (int*)(zbuf + (size_t)N * 16);    // [N+1] (+pad)
  int* cnt    = rowptr + (N + 4);                 // [N]      (memset region)
  int* bflag  = cnt + N;                          // [256]    (memset region)
  int* bsum   = bflag + 256;                      // [256]
  int* cursor = bsum + 256;                       // [N]
  int* colx   = cursor + N;                       // [E]

  const int nb = (N + 255) / 256;  // <=256 required by k_scan lookback
  const int eb = (E + 255) / 256;

  hipMemsetAsync(cnt, 0, ((size_t)N + 256) * 4, stream);  // cnt + bflag
  k_hist<<<eb, 256, 0, stream>>>(dstv, cnt, E);
  k_scan<<<nb, 256, 0, stream>>>(cnt, rowptr, cursor, bsum, bflag, N, E);
  k_scatter<<<eb, 256, 0, stream>>>(srcv, dstv, cursor, colx, E);
  k_prep_w<<<384, 256, 0, stream>>>(W1, W2, w1th, w1tl, w2th, w2tl);

  // XCD-aligned swizzled 1-D grid: 16 blocks per group of 8 row blocks
  const int nrb = (N + 127) / 128;
  const int gemm_blocks = ((nrb + 7) / 8) * 16;
  const int wb = (N + 3) / 4;  // one wave per node

  k_gemm_mfma<1><<<gemm_blocks, 256, 0, stream>>>(x, nullptr, w1th, w1tl,
                                                  h1, N, 128,
                                                  as1, ad1, a_s1, a_d1);
  k_aggr<1><<<wb, 256, 0, stream>>>(h1, rowptr, colx, a_s1, a_d1, b1,
                                    hb_h, hb_l, nullptr, N);
  k_gemm_mfma<0><<<gemm_blocks, 256, 0, stream>>>(hb_h, hb_l, w2th, w2tl,
                                                  h1, N, 256,
                                                  as2, ad2, a_s2, a_d2);
  k_aggr<2><<<wb, 256, 0, stream>>>(h1, rowptr, colx, a_s2, a_d2, b2,
                                    nullptr, nullptr, out, N);
}